// Round 2
// baseline (16998.003 us; speedup 1.0000x reference)
//
#include <hip/hip_runtime.h>
#include <math.h>

#define VSZ 50000
#define OOVN 50
#define VE 50050
#define EMB 256
#define HE 512
#define HD 512
#define NB 32
#define SRC 400
#define TDD 30
#define G3 1536   // 3*HE = 3*HD
#define ESCAN_NBLK 128

__device__ __forceinline__ float sigmf(float x) { return 1.f / (1.f + expf(-x)); }

// out[c*rows + r] = in[r*cols + c]
__global__ __launch_bounds__(256) void transpose_kernel(const float* __restrict__ in,
                                                        float* __restrict__ out,
                                                        int rows, int cols) {
    int idx = blockIdx.x * 256 + threadIdx.x;
    if (idx >= rows * cols) return;
    int r = idx / cols, c = idx % cols;
    out[c * rows + r] = in[idx];
}

// gi[(s*NB+n)*G3 + c] = bih[c] + sum_e embed[ids[n*steps+s]][e] * WihT[e*G3+c]
__global__ __launch_bounds__(256) void gi_kernel(const int* __restrict__ ids,
                                                 const float* __restrict__ embed,
                                                 const float* __restrict__ WihT,
                                                 const float* __restrict__ bih,
                                                 float* __restrict__ gi, int steps) {
    __shared__ float sx[16][EMB];
    __shared__ int stok[16];
    int tid = threadIdx.x;
    int g0 = blockIdx.x * 16;
    if (tid < 16) {
        int row = g0 + tid;
        int s = row / NB, n = row % NB;
        stok[tid] = ids[n * steps + s];
    }
    __syncthreads();
    for (int r = 0; r < 16; ++r) sx[r][tid] = embed[(size_t)stok[r] * EMB + tid];
    __syncthreads();
    int c = blockIdx.y * 256 + tid;
    float b = bih[c];
    float acc[16];
#pragma unroll
    for (int r = 0; r < 16; ++r) acc[r] = b;
    for (int e = 0; e < EMB; e += 4) {
        float w0 = WihT[(size_t)(e + 0) * G3 + c];
        float w1 = WihT[(size_t)(e + 1) * G3 + c];
        float w2 = WihT[(size_t)(e + 2) * G3 + c];
        float w3 = WihT[(size_t)(e + 3) * G3 + c];
#pragma unroll
        for (int r = 0; r < 16; ++r) {
            float4 x4 = *(const float4*)&sx[r][e];
            acc[r] += x4.x * w0 + x4.y * w1 + x4.z * w2 + x4.w * w3;
        }
    }
#pragma unroll
    for (int r = 0; r < 16; ++r) gi[(size_t)(g0 + r) * G3 + c] = acc[r];
}

// ---------------- persistent encoder scan (software barrier, NOT cooperative) ----
// grid 128 blocks: bid>>6 = direction, bid&63 = j-slice of 8 columns.
// 512 threads: jl = tid&7, kh = (tid>>3)&7 (k-chunk of 64), ng = tid>>6 (4 n each).
// Whh slice in LDS once (chunk stride 68 floats -> 8 distinct bank groups).
// h double-buffered in global; per-step counter barrier in cnt[t].
__global__ __launch_bounds__(512) void enc_scan_kernel(
    const float* __restrict__ giF, const float* __restrict__ giB,
    const float* __restrict__ WhhF, const float* __restrict__ WhhB,
    const float* __restrict__ bhhF, const float* __restrict__ bhhB,
    float* __restrict__ hF0, float* __restrict__ hF1,
    float* __restrict__ hB0, float* __restrict__ hB1,
    float* __restrict__ enc, unsigned int* __restrict__ cnt) {
    const int bid = blockIdx.x;
    const int z = bid >> 6;
    const int j0 = (bid & 63) * 8;
    const float* gi  = z ? giB : giF;
    const float* Whh = z ? WhhB : WhhF;
    const float* bhh = z ? bhhB : bhhF;
    float* hbuf[2];
    hbuf[0] = z ? hB0 : hF0;
    hbuf[1] = z ? hB1 : hF1;

    __shared__ float wlds[24 * 544];   // [g*8+jl][kh*68 + i]   52.2 KB
    __shared__ float hlds[32 * 544];   // [n][kh*68 + i]        69.6 KB

    const int tid = threadIdx.x;

    // one-time weight preload (coalesced: one 512-float row per pass)
    for (int idx = tid; idx < 24 * 512; idx += 512) {
        int row = idx >> 9;            // g*8+jl
        int k   = idx & 511;
        int g   = row >> 3, jl = row & 7;
        wlds[row * 544 + (k >> 6) * 68 + (k & 63)] =
            Whh[(size_t)(g * 512 + j0 + jl) * 512 + k];
    }

    const int jl = tid & 7;
    const int kh = (tid >> 3) & 7;
    const int ng = tid >> 6;
    const int kbase = kh * 68;
    const float* wR = &wlds[(0 * 8 + jl) * 544 + kbase];
    const float* wZ = &wlds[(1 * 8 + jl) * 544 + kbase];
    const float* wN = &wlds[(2 * 8 + jl) * 544 + kbase];

    for (int t = 0; t < SRC; ++t) {
        const float* hin = hbuf[t & 1];
        float* hout = hbuf[(t + 1) & 1];
        // stage h[32][512] -> chunk-padded LDS (float4, coalesced)
        for (int idx = tid; idx < 32 * 128; idx += 512) {
            int nn = idx >> 7, kq = (idx & 127) << 2;
            float4 v = *(const float4*)&hin[nn * 512 + kq];
            *(float4*)&hlds[nn * 544 + (kq >> 6) * 68 + (kq & 63)] = v;
        }
        __syncthreads();

        float aR[4] = {0.f, 0.f, 0.f, 0.f};
        float aZ[4] = {0.f, 0.f, 0.f, 0.f};
        float aN[4] = {0.f, 0.f, 0.f, 0.f};
        const float* h0p = &hlds[(ng * 4 + 0) * 544 + kbase];
        const float* h1p = &hlds[(ng * 4 + 1) * 544 + kbase];
        const float* h2p = &hlds[(ng * 4 + 2) * 544 + kbase];
        const float* h3p = &hlds[(ng * 4 + 3) * 544 + kbase];
#pragma unroll
        for (int i = 0; i < 64; i += 4) {
            float4 wr = *(const float4*)&wR[i];
            float4 wz = *(const float4*)&wZ[i];
            float4 wn = *(const float4*)&wN[i];
            float4 ha = *(const float4*)&h0p[i];
            float4 hb = *(const float4*)&h1p[i];
            float4 hc = *(const float4*)&h2p[i];
            float4 hd = *(const float4*)&h3p[i];
            aR[0] += ha.x*wr.x + ha.y*wr.y + ha.z*wr.z + ha.w*wr.w;
            aZ[0] += ha.x*wz.x + ha.y*wz.y + ha.z*wz.z + ha.w*wz.w;
            aN[0] += ha.x*wn.x + ha.y*wn.y + ha.z*wn.z + ha.w*wn.w;
            aR[1] += hb.x*wr.x + hb.y*wr.y + hb.z*wr.z + hb.w*wr.w;
            aZ[1] += hb.x*wz.x + hb.y*wz.y + hb.z*wz.z + hb.w*wz.w;
            aN[1] += hb.x*wn.x + hb.y*wn.y + hb.z*wn.z + hb.w*wn.w;
            aR[2] += hc.x*wr.x + hc.y*wr.y + hc.z*wr.z + hc.w*wr.w;
            aZ[2] += hc.x*wz.x + hc.y*wz.y + hc.z*wz.z + hc.w*wz.w;
            aN[2] += hc.x*wn.x + hc.y*wn.y + hc.z*wn.z + hc.w*wn.w;
            aR[3] += hd.x*wr.x + hd.y*wr.y + hd.z*wr.z + hd.w*wr.w;
            aZ[3] += hd.x*wz.x + hd.y*wz.y + hd.z*wz.z + hd.w*wz.w;
            aN[3] += hd.x*wn.x + hd.y*wn.y + hd.z*wn.z + hd.w*wn.w;
        }
        // reduce across kh (tid bits 3-5, within the 64-lane wave)
#pragma unroll
        for (int r = 0; r < 4; ++r) {
            aR[r] += __shfl_xor(aR[r], 8);  aR[r] += __shfl_xor(aR[r], 16); aR[r] += __shfl_xor(aR[r], 32);
            aZ[r] += __shfl_xor(aZ[r], 8);  aZ[r] += __shfl_xor(aZ[r], 16); aZ[r] += __shfl_xor(aZ[r], 32);
            aN[r] += __shfl_xor(aN[r], 8);  aN[r] += __shfl_xor(aN[r], 16); aN[r] += __shfl_xor(aN[r], 32);
        }
        if (kh == 0) {
            int s = z ? (SRC - 1 - t) : t;
            int j = j0 + jl;
#pragma unroll
            for (int r = 0; r < 4; ++r) {
                int n = ng * 4 + r;
                const float* gir = gi + (size_t)(s * NB + n) * G3;
                float rr  = sigmf(gir[j] + bhh[j] + aR[r]);
                float zz  = sigmf(gir[512 + j] + bhh[512 + j] + aZ[r]);
                float nn2 = tanhf(gir[1024 + j] + bhh[1024 + j] + rr * aN[r]);
                float hp  = hlds[n * 544 + (j >> 6) * 68 + (j & 63)];
                float hnew = (1.f - zz) * nn2 + zz * hp;
                hout[n * 512 + j] = hnew;
                enc[(size_t)(n * SRC + s) * 1024 + z * 512 + j] = hnew;
            }
        }
        __threadfence();
        __syncthreads();
        if (tid == 0) {
            __hip_atomic_fetch_add(&cnt[t], 1u, __ATOMIC_RELEASE, __HIP_MEMORY_SCOPE_AGENT);
            while (__hip_atomic_load(&cnt[t], __ATOMIC_ACQUIRE, __HIP_MEMORY_SCOPE_AGENT) < ESCAN_NBLK)
                __builtin_amdgcn_s_sleep(2);
        }
        __syncthreads();
    }
}

// Decoder GRU step. grid (16,4), block 256 = 8n x 32j
__global__ __launch_bounds__(256) void dec_step_kernel(
    const float* __restrict__ gi, const float* __restrict__ WhhT,
    const float* __restrict__ bhh, const float* __restrict__ hin,
    float* __restrict__ hout, int t) {
    __shared__ float sh[8][HD];
    int tid = threadIdx.x;
    int n0 = blockIdx.y * 8;
    for (int i = tid; i < 8 * HD; i += 256)
        sh[i >> 9][i & 511] = hin[(size_t)(n0 + (i >> 9)) * HD + (i & 511)];
    __syncthreads();
    int j = blockIdx.x * 32 + (tid & 31);
    int nl = tid >> 5;
    int n = n0 + nl;
    float aR = bhh[j], aZ = bhh[HD + j], aN = bhh[2 * HD + j];
    for (int k = 0; k < HD; k += 4) {
        float4 h4 = *(const float4*)&sh[nl][k];
        const float* w0 = WhhT + (size_t)(k + 0) * G3;
        const float* w1 = WhhT + (size_t)(k + 1) * G3;
        const float* w2 = WhhT + (size_t)(k + 2) * G3;
        const float* w3 = WhhT + (size_t)(k + 3) * G3;
        aR += h4.x * w0[j] + h4.y * w1[j] + h4.z * w2[j] + h4.w * w3[j];
        aZ += h4.x * w0[HD + j] + h4.y * w1[HD + j] + h4.z * w2[HD + j] + h4.w * w3[HD + j];
        aN += h4.x * w0[2 * HD + j] + h4.y * w1[2 * HD + j] + h4.z * w2[2 * HD + j] + h4.w * w3[2 * HD + j];
    }
    const float* gir = gi + (size_t)(t * NB + n) * G3;
    float r  = sigmf(gir[j] + aR);
    float zz = sigmf(gir[HD + j] + aZ);
    float nn = tanhf(gir[2 * HD + j] + r * aN);
    float hp = sh[nl][j];
    hout[(size_t)n * HD + j] = (1.f - zz) * nn + zz * hp;
}

// key_proj: kp[(n*SRC+s)*512 + c] = sum_k enc[row][k]*Wk[k*512+c]. 8 rows/block.
__global__ __launch_bounds__(256) void keyproj_kernel(const float* __restrict__ enc,
                                                      const float* __restrict__ Wk,
                                                      float* __restrict__ kp) {
    __shared__ float sx[8][1024];
    int tid = threadIdx.x;
    int g0 = blockIdx.x * 8;
    for (int i = tid; i < 8 * 1024; i += 256)
        sx[i >> 10][i & 1023] = enc[(size_t)(g0 + (i >> 10)) * 1024 + (i & 1023)];
    __syncthreads();
    int c = blockIdx.y * 256 + tid;
    float acc[8];
#pragma unroll
    for (int r = 0; r < 8; ++r) acc[r] = 0.f;
    for (int k = 0; k < 1024; k += 4) {
        float w0 = Wk[(size_t)(k + 0) * 512 + c];
        float w1 = Wk[(size_t)(k + 1) * 512 + c];
        float w2 = Wk[(size_t)(k + 2) * 512 + c];
        float w3 = Wk[(size_t)(k + 3) * 512 + c];
#pragma unroll
        for (int r = 0; r < 8; ++r) {
            float4 x4 = *(const float4*)&sx[r][k];
            acc[r] += x4.x * w0 + x4.y * w1 + x4.z * w2 + x4.w * w3;
        }
    }
#pragma unroll
    for (int r = 0; r < 8; ++r) kp[(size_t)(g0 + r) * 512 + c] = acc[r];
}

// q_all[tn][c] = battn[c] + hD_all[tn] . Wd[:,c]; 8 rows/block, grid (120,2)
__global__ __launch_bounds__(256) void qall_kernel(const float* __restrict__ hall,
                                                   const float* __restrict__ Wd,
                                                   const float* __restrict__ battn,
                                                   float* __restrict__ qall) {
    __shared__ float sx[8][512];
    int tid = threadIdx.x;
    int g0 = blockIdx.x * 8;
    for (int i = tid; i < 8 * 512; i += 256)
        sx[i >> 9][i & 511] = hall[(size_t)(g0 + (i >> 9)) * 512 + (i & 511)];
    __syncthreads();
    int c = blockIdx.y * 256 + tid;
    float b = battn[c];
    float acc[8];
#pragma unroll
    for (int r = 0; r < 8; ++r) acc[r] = b;
    for (int k = 0; k < 512; k += 4) {
        float w0 = Wd[(size_t)(k + 0) * 512 + c];
        float w1 = Wd[(size_t)(k + 1) * 512 + c];
        float w2 = Wd[(size_t)(k + 2) * 512 + c];
        float w3 = Wd[(size_t)(k + 3) * 512 + c];
#pragma unroll
        for (int r = 0; r < 8; ++r) {
            float4 x4 = *(const float4*)&sx[r][k];
            acc[r] += x4.x * w0 + x4.y * w1 + x4.z * w2 + x4.w * w3;
        }
    }
#pragma unroll
    for (int r = 0; r < 8; ++r) qall[(size_t)(g0 + r) * 512 + c] = acc[r];
}

// e_all[(tn)*SRC+s] = v . tanh(kp[n,s,:] + q_all[tn]) + mask ; 4 rows/block
__global__ __launch_bounds__(256) void escoreall_kernel(const float* __restrict__ kp,
                                                        const float* __restrict__ qall,
                                                        const float* __restrict__ vvec,
                                                        const float* __restrict__ mask,
                                                        float* __restrict__ e) {
    __shared__ float sq[512];
    int tid = threadIdx.x;
    int row0 = blockIdx.x * 4;
    int tn = row0 / SRC;    // 4 | SRC so all 4 rows share tn
    int n = tn % NB;
    sq[tid] = qall[(size_t)tn * 512 + tid];
    sq[256 + tid] = qall[(size_t)tn * 512 + 256 + tid];
    __syncthreads();
    int w = tid >> 6, lane = tid & 63;
    int row = row0 + w;
    int s = row % SRC;
    const float* kpr = kp + (size_t)(n * SRC + s) * 512;
    float acc = 0.f;
#pragma unroll
    for (int i = 0; i < 8; ++i) {
        int d = lane + i * 64;
        acc += vvec[d] * tanhf(kpr[d] + sq[d]);
    }
    for (int off = 32; off; off >>= 1) acc += __shfl_down(acc, off, 64);
    if (lane == 0) e[row] = acc + (1.f - mask[n * SRC + s]) * (-1e10f);
}

// softmax over SRC per row, in place. block per row (works for any grid of rows).
__global__ __launch_bounds__(256) void softmaxS_kernel(float* __restrict__ e) {
    __shared__ float red[256];
    int n = blockIdx.x, tid = threadIdx.x;
    float* row = e + (size_t)n * SRC;
    float m = -3.4e38f;
    for (int s = tid; s < SRC; s += 256) m = fmaxf(m, row[s]);
    red[tid] = m; __syncthreads();
    for (int off = 128; off; off >>= 1) { if (tid < off) red[tid] = fmaxf(red[tid], red[tid + off]); __syncthreads(); }
    m = red[0]; __syncthreads();
    float sum = 0.f;
    for (int s = tid; s < SRC; s += 256) sum += expf(row[s] - m);
    red[tid] = sum; __syncthreads();
    for (int off = 128; off; off >>= 1) { if (tid < off) red[tid] += red[tid + off]; __syncthreads(); }
    float inv = 1.f / red[0]; __syncthreads();
    for (int s = tid; s < SRC; s += 256) row[s] = expf(row[s] - m) * inv;
}

// ctx_all[(t*NB+n)*1024+d] = sum_s attn[(t*NB+n)*SRC+s]*enc[n,s,d]
// block (n, dchunk); enc read ONCE for all 30 t. grid (32,4)
__global__ __launch_bounds__(256) void ctxall_kernel(const float* __restrict__ attn,
                                                     const float* __restrict__ enc,
                                                     float* __restrict__ ctxall) {
    __shared__ float sa[TDD * SRC];   // 48 KB
    int n = blockIdx.x, tid = threadIdx.x;
    for (int i = tid; i < TDD * SRC; i += 256) {
        int t = i / SRC, s = i - t * SRC;
        sa[i] = attn[(size_t)(t * NB + n) * SRC + s];
    }
    __syncthreads();
    int d = blockIdx.y * 256 + tid;
    const float* er = enc + (size_t)n * SRC * 1024 + d;
    float acc[TDD];
#pragma unroll
    for (int t = 0; t < TDD; ++t) acc[t] = 0.f;
    for (int s = 0; s < SRC; s += 4) {
        float e0 = er[(size_t)(s + 0) * 1024];
        float e1 = er[(size_t)(s + 1) * 1024];
        float e2 = er[(size_t)(s + 2) * 1024];
        float e3 = er[(size_t)(s + 3) * 1024];
#pragma unroll
        for (int t = 0; t < TDD; ++t) {
            float4 a4 = *(const float4*)&sa[t * SRC + s];
            acc[t] += a4.x * e0 + a4.y * e1 + a4.z * e2 + a4.w * e3;
        }
    }
#pragma unroll
    for (int t = 0; t < TDD; ++t) ctxall[(size_t)(t * NB + n) * 1024 + d] = acc[t];
}

// pgen_all[tn] = sigmoid([xi, ctx, h] . Wp + bp); block per tn, grid 960
__global__ __launch_bounds__(256) void pgenall_kernel(const int* __restrict__ trg_ids,
                                                      const float* __restrict__ embed,
                                                      const float* __restrict__ ctxall,
                                                      const float* __restrict__ hall,
                                                      const float* __restrict__ Wp,
                                                      const float* __restrict__ bp,
                                                      float* __restrict__ pgenall) {
    __shared__ float red[256];
    int tn = blockIdx.x, tid = threadIdx.x;
    int t = tn / NB, n = tn % NB;
    int tok = trg_ids[n * TDD + t];
    float acc = 0.f;
    for (int i = tid; i < 1792; i += 256) {
        float val;
        if (i < 256) val = embed[(size_t)tok * EMB + i];
        else if (i < 1280) val = ctxall[(size_t)tn * 1024 + (i - 256)];
        else val = hall[(size_t)tn * 512 + (i - 1280)];
        acc += val * Wp[i];
    }
    red[tid] = acc; __syncthreads();
    for (int off = 128; off; off >>= 1) { if (tid < off) red[tid] += red[tid + off]; __syncthreads(); }
    if (tid == 0) pgenall[tn] = 1.f / (1.f + expf(-(red[0] + bp[0])));
}

// hid1_all[tn][c] = b1[c] + [h,ctx] . W1[:,c]; 8 rows/block, grid (120,2)
__global__ __launch_bounds__(256) void hid1all_kernel(const float* __restrict__ hall,
                                                      const float* __restrict__ ctxall,
                                                      const float* __restrict__ W1,
                                                      const float* __restrict__ b1,
                                                      float* __restrict__ hid1all) {
    __shared__ float sc[8][1536];   // 48 KB
    int tid = threadIdx.x;
    int g0 = blockIdx.x * 8;
    for (int i = tid; i < 8 * 512; i += 256)
        sc[i >> 9][i & 511] = hall[(size_t)(g0 + (i >> 9)) * 512 + (i & 511)];
    for (int i = tid; i < 8 * 1024; i += 256)
        sc[i >> 10][512 + (i & 1023)] = ctxall[(size_t)(g0 + (i >> 10)) * 1024 + (i & 1023)];
    __syncthreads();
    int c = blockIdx.y * 256 + tid;
    float acc[8];
    float b = b1[c];
#pragma unroll
    for (int r = 0; r < 8; ++r) acc[r] = b;
    for (int k = 0; k < 1536; k += 4) {
        float w0 = W1[(size_t)(k + 0) * 512 + c];
        float w1 = W1[(size_t)(k + 1) * 512 + c];
        float w2 = W1[(size_t)(k + 2) * 512 + c];
        float w3 = W1[(size_t)(k + 3) * 512 + c];
#pragma unroll
        for (int r = 0; r < 8; ++r) {
            float4 x4 = *(const float4*)&sc[r][k];
            acc[r] += x4.x * w0 + x4.y * w1 + x4.z * w2 + x4.w * w3;
        }
    }
#pragma unroll
    for (int r = 0; r < 8; ++r) hid1all[(size_t)(g0 + r) * 512 + c] = acc[r];
}

// logits_all: 32-row groups; grid (196, 30). thread per j, 32 rows in registers.
__global__ __launch_bounds__(256) void logitsall_kernel(const float* __restrict__ hid1,
                                                        const float* __restrict__ W2,
                                                        const float* __restrict__ b2,
                                                        float* __restrict__ logits) {
    __shared__ float sh[32][512];   // 64 KB
    int tid = threadIdx.x;
    int r0 = blockIdx.y * 32;
    for (int i = tid; i < 32 * 512; i += 256) sh[i >> 9][i & 511] = hid1[(size_t)r0 * 512 + i];
    __syncthreads();
    int j = blockIdx.x * 256 + tid;
    if (j >= VSZ) return;
    float acc[32];
#pragma unroll
    for (int r = 0; r < 32; ++r) acc[r] = 0.f;
    for (int k = 0; k < 512; k += 4) {
        float w0 = W2[(size_t)(k + 0) * VSZ + j];
        float w1 = W2[(size_t)(k + 1) * VSZ + j];
        float w2 = W2[(size_t)(k + 2) * VSZ + j];
        float w3 = W2[(size_t)(k + 3) * VSZ + j];
#pragma unroll
        for (int r = 0; r < 32; ++r) {
            float4 h4 = *(const float4*)&sh[r][k];
            acc[r] += h4.x * w0 + h4.y * w1 + h4.z * w2 + h4.w * w3;
        }
    }
    float bb = b2[j];
#pragma unroll
    for (int r = 0; r < 32; ++r) logits[(size_t)(r0 + r) * VSZ + j] = acc[r] + bb;
}

// softmax over V, scale by p_gen, write out row (incl. zero OOV tail); block per tn
__global__ __launch_bounds__(1024) void outall_kernel(const float* __restrict__ logits,
                                                      const float* __restrict__ pgenall,
                                                      float* __restrict__ out) {
    __shared__ float red[1024];
    int tn = blockIdx.x, tid = threadIdx.x;
    int t = tn / NB, n = tn % NB;
    const float* lrow = logits + (size_t)tn * VSZ;
    float m = -3.4e38f;
    for (int j = tid; j < VSZ; j += 1024) m = fmaxf(m, lrow[j]);
    red[tid] = m; __syncthreads();
    for (int off = 512; off; off >>= 1) { if (tid < off) red[tid] = fmaxf(red[tid], red[tid + off]); __syncthreads(); }
    m = red[0]; __syncthreads();
    float sum = 0.f;
    for (int j = tid; j < VSZ; j += 1024) sum += expf(lrow[j] - m);
    red[tid] = sum; __syncthreads();
    for (int off = 512; off; off >>= 1) { if (tid < off) red[tid] += red[tid + off]; __syncthreads(); }
    float inv = pgenall[tn] / red[0];
    float* orow = out + (size_t)(n * TDD + t) * VE;
    for (int j = tid; j < VE; j += 1024) orow[j] = (j < VSZ) ? expf(lrow[j] - m) * inv : 0.f;
}

// out[n, t, ptr[n,s]] += (1-p_gen[tn]) * attn[tn,s] for all t,n,s
__global__ __launch_bounds__(256) void scatterall_kernel(const int* __restrict__ ptr,
                                                         const float* __restrict__ attn,
                                                         const float* __restrict__ pgenall,
                                                         float* __restrict__ out) {
    int f = blockIdx.x * 256 + threadIdx.x;
    if (f >= TDD * NB * SRC) return;
    int tn = f / SRC;
    int s = f - tn * SRC;
    int t = tn / NB, n = tn % NB;
    float w = (1.f - pgenall[tn]) * attn[f];
    atomicAdd(&out[(size_t)(n * TDD + t) * VE + ptr[n * SRC + s]], w);
}

extern "C" void kernel_launch(void* const* d_in, const int* in_sizes, int n_in,
                              void* d_out, int out_size, void* d_ws, size_t ws_size,
                              hipStream_t stream) {
    const int*   src_ids  = (const int*)d_in[0];
    const float* src_mask = (const float*)d_in[1];
    const int*   trg_ids  = (const int*)d_in[2];
    const int*   ptr_idx  = (const int*)d_in[3];
    const float* embed    = (const float*)d_in[4];
    const float* Wih_f = (const float*)d_in[5];
    const float* Whh_f = (const float*)d_in[6];
    const float* bih_f = (const float*)d_in[7];
    const float* bhh_f = (const float*)d_in[8];
    const float* Wih_b = (const float*)d_in[9];
    const float* Whh_b = (const float*)d_in[10];
    const float* bih_b = (const float*)d_in[11];
    const float* bhh_b = (const float*)d_in[12];
    const float* Wih_d = (const float*)d_in[13];
    const float* Whh_d = (const float*)d_in[14];
    const float* bih_d = (const float*)d_in[15];
    const float* bhh_d = (const float*)d_in[16];
    const float* Wk    = (const float*)d_in[17];
    const float* Wd    = (const float*)d_in[18];
    const float* battn = (const float*)d_in[19];
    const float* vvec  = (const float*)d_in[20];
    const float* W1    = (const float*)d_in[21];
    const float* b1    = (const float*)d_in[22];
    const float* W2    = (const float*)d_in[23];
    const float* b2    = (const float*)d_in[24];
    const float* Wp    = (const float*)d_in[25];
    const float* bp    = (const float*)d_in[26];
    float* out = (float*)d_out;

    float* w = (float*)d_ws;
    float* WihTf = w; w += 256 * G3;
    float* WihTb = w; w += 256 * G3;
    float* WihTd = w; w += 256 * G3;
    float* WhhTd = w; w += 512 * G3;
    float* giF = w; w += (size_t)SRC * NB * G3;   // dead after enc_scan
    float* giB = w; w += (size_t)SRC * NB * G3;   // dead after enc_scan
    float* giD = w; w += (size_t)TDD * NB * G3;   // dead after dec recurrence
    float* enc = w; w += (size_t)NB * SRC * 1024; // dead after ctx_all
    float* kp  = w; w += (size_t)NB * SRC * 512;  // dead after escore_all
    float* hF0 = w; w += NB * HE;
    float* hF1 = w; w += NB * HE;
    float* hB0 = w; w += NB * HE;
    float* hB1 = w; w += NB * HE;
    float* h0d = w; w += NB * HD;
    float* hD_all = w; w += (size_t)TDD * NB * HD;
    float* q_all  = w; w += (size_t)TDD * NB * 512;
    float* e_all  = w; w += (size_t)TDD * NB * SRC;
    float* ctx_all = w; w += (size_t)TDD * NB * 1024;
    float* hid1_all = w; w += (size_t)TDD * NB * 512;
    float* pgen_all = w; w += 1024;
    unsigned int* cnt = (unsigned int*)w; w += 512;
    // logits_all (960*50000 floats = 48M) aliases the dead giF..enc-prefix region
    float* logits_all = giF;

    // ---- weight transposes (Wih x3 for gi; WhhTd for decoder steps) ----
    transpose_kernel<<<(G3 * 256 + 255) / 256, 256, 0, stream>>>(Wih_f, WihTf, G3, 256);
    transpose_kernel<<<(G3 * 256 + 255) / 256, 256, 0, stream>>>(Wih_b, WihTb, G3, 256);
    transpose_kernel<<<(G3 * 256 + 255) / 256, 256, 0, stream>>>(Wih_d, WihTd, G3, 256);
    transpose_kernel<<<(G3 * 512 + 255) / 256, 256, 0, stream>>>(Whh_d, WhhTd, G3, 512);

    // ---- input-gate precompute ----
    gi_kernel<<<dim3(SRC * NB / 16, 6), 256, 0, stream>>>(src_ids, embed, WihTf, bih_f, giF, SRC);
    gi_kernel<<<dim3(SRC * NB / 16, 6), 256, 0, stream>>>(src_ids, embed, WihTb, bih_b, giB, SRC);
    gi_kernel<<<dim3(TDD * NB / 16, 6), 256, 0, stream>>>(trg_ids, embed, WihTd, bih_d, giD, TDD);

    hipMemsetAsync(hF0, 0, NB * HE * sizeof(float), stream);
    hipMemsetAsync(hB0, 0, NB * HE * sizeof(float), stream);
    hipMemsetAsync(h0d, 0, NB * HD * sizeof(float), stream);
    hipMemsetAsync(cnt, 0, 512 * sizeof(unsigned int), stream);

    // ---- encoder scan: ONE persistent kernel, software barrier (128 blocks, 1/CU) ----
    enc_scan_kernel<<<ESCAN_NBLK, 512, 0, stream>>>(
        giF, giB, Whh_f, Whh_b, bhh_f, bhh_b,
        hF0, hF1, hB0, hB1, enc, cnt);

    keyproj_kernel<<<dim3(NB * SRC / 8, 2), 256, 0, stream>>>(enc, Wk, kp);

    // ---- decoder GRU recurrence (h does not depend on attention) ----
    for (int t = 0; t < TDD; ++t) {
        const float* hi = (t == 0) ? h0d : (hD_all + (size_t)(t - 1) * NB * HD);
        float* ho = hD_all + (size_t)t * NB * HD;
        dec_step_kernel<<<dim3(16, 4), 256, 0, stream>>>(giD, WhhTd, bhh_d, hi, ho, t);
    }

    // ---- fully batched decoder head over all 30 steps ----
    qall_kernel<<<dim3(TDD * NB / 8, 2), 256, 0, stream>>>(hD_all, Wd, battn, q_all);
    escoreall_kernel<<<TDD * NB * SRC / 4, 256, 0, stream>>>(kp, q_all, vvec, src_mask, e_all);
    softmaxS_kernel<<<TDD * NB, 256, 0, stream>>>(e_all);
    ctxall_kernel<<<dim3(NB, 4), 256, 0, stream>>>(e_all, enc, ctx_all);
    pgenall_kernel<<<TDD * NB, 256, 0, stream>>>(trg_ids, embed, ctx_all, hD_all, Wp, bp, pgen_all);
    hid1all_kernel<<<dim3(TDD * NB / 8, 2), 256, 0, stream>>>(hD_all, ctx_all, W1, b1, hid1_all);
    logitsall_kernel<<<dim3((VSZ + 255) / 256, TDD), 256, 0, stream>>>(hid1_all, W2, b2, logits_all);
    outall_kernel<<<TDD * NB, 1024, 0, stream>>>(logits_all, pgen_all, out);
    scatterall_kernel<<<(TDD * NB * SRC + 255) / 256, 256, 0, stream>>>(ptr_idx, e_all, pgen_all, out);
}

// Round 3
// 8733.732 us; speedup vs baseline: 1.9462x; 1.9462x over previous
//
#include <hip/hip_runtime.h>
#include <math.h>

#define VSZ 50000
#define OOVN 50
#define VE 50050
#define EMB 256
#define HE 512
#define HD 512
#define NB 32
#define SRC 400
#define TDD 30
#define G3 1536   // 3*HE = 3*HD
#define ENC_PER_DIR 128
#define DEC_NBLK 128

__device__ __forceinline__ float sigmf(float x) { return 1.f / (1.f + expf(-x)); }

// out[c*rows + r] = in[r*cols + c]
__global__ __launch_bounds__(256) void transpose_kernel(const float* __restrict__ in,
                                                        float* __restrict__ out,
                                                        int rows, int cols) {
    int idx = blockIdx.x * 256 + threadIdx.x;
    if (idx >= rows * cols) return;
    int r = idx / cols, c = idx % cols;
    out[c * rows + r] = in[idx];
}

// gi[(s*NB+n)*G3 + c] = bih[c] + sum_e embed[ids[n*steps+s]][e] * WihT[e*G3+c]
__global__ __launch_bounds__(256) void gi_kernel(const int* __restrict__ ids,
                                                 const float* __restrict__ embed,
                                                 const float* __restrict__ WihT,
                                                 const float* __restrict__ bih,
                                                 float* __restrict__ gi, int steps) {
    __shared__ float sx[16][EMB];
    __shared__ int stok[16];
    int tid = threadIdx.x;
    int g0 = blockIdx.x * 16;
    if (tid < 16) {
        int row = g0 + tid;
        int s = row / NB, n = row % NB;
        stok[tid] = ids[n * steps + s];
    }
    __syncthreads();
    for (int r = 0; r < 16; ++r) sx[r][tid] = embed[(size_t)stok[r] * EMB + tid];
    __syncthreads();
    int c = blockIdx.y * 256 + tid;
    float b = bih[c];
    float acc[16];
#pragma unroll
    for (int r = 0; r < 16; ++r) acc[r] = b;
    for (int e = 0; e < EMB; e += 4) {
        float w0 = WihT[(size_t)(e + 0) * G3 + c];
        float w1 = WihT[(size_t)(e + 1) * G3 + c];
        float w2 = WihT[(size_t)(e + 2) * G3 + c];
        float w3 = WihT[(size_t)(e + 3) * G3 + c];
#pragma unroll
        for (int r = 0; r < 16; ++r) {
            float4 x4 = *(const float4*)&sx[r][e];
            acc[r] += x4.x * w0 + x4.y * w1 + x4.z * w2 + x4.w * w3;
        }
    }
#pragma unroll
    for (int r = 0; r < 16; ++r) gi[(size_t)(g0 + r) * G3 + c] = acc[r];
}

// ---------------- persistent encoder scan, L2-bypass barrier ----------------
// grid 256: bid>>7 = dir, (bid&127)*4 = j0. 512 threads: jl=tid&3, kh=(tid>>2)&15,
// ng=tid>>6 (4 n each). Weights in REGISTERS (3 gates x 32 k-chunk = 96 VGPR).
// h exchanged via agent-scope (sc0 sc1) write-through stores + bypass loads:
// no threadfence, no L2 writeback/invalidate. Relaxed counter barrier.
__global__ __launch_bounds__(512) void enc_scan_kernel(
    const float* __restrict__ giF, const float* __restrict__ giB,
    const float* __restrict__ WhhF, const float* __restrict__ WhhB,
    const float* __restrict__ bhhF, const float* __restrict__ bhhB,
    float* __restrict__ hF0, float* __restrict__ hF1,
    float* __restrict__ hB0, float* __restrict__ hB1,
    float* __restrict__ enc, unsigned int* __restrict__ cnt) {
    const int bid = blockIdx.x;
    const int z = bid >> 7;
    const int j0 = (bid & 127) * 4;
    const float* gi  = z ? giB : giF;
    const float* Whh = z ? WhhB : WhhF;
    const float* bhh = z ? bhhB : bhhF;
    float* hbuf[2];
    hbuf[0] = z ? hB0 : hF0;
    hbuf[1] = z ? hB1 : hF1;
    unsigned int* cntd = cnt + (size_t)z * 512;

    __shared__ float hlds[32 * 576];   // [n][kh*36 + i]  73.7 KB

    const int tid = threadIdx.x;
    const int jl = tid & 3;
    const int kh = (tid >> 2) & 15;
    const int ng = tid >> 6;
    const int j  = j0 + jl;
    const int kbase = kh * 36;

    // ---- weights to registers: 3 gates x 8 float4 (k-chunk of 32) ----
    float4 wreg[3][8];
#pragma unroll
    for (int g = 0; g < 3; ++g) {
        const float* wp = Whh + (size_t)(g * 512 + j) * 512 + kh * 32;
#pragma unroll
        for (int i = 0; i < 8; ++i) wreg[g][i] = *(const float4*)&wp[i * 4];
    }
    const float bR = bhh[j], bZ = bhh[512 + j], bN = bhh[1024 + j];

    for (int t = 0; t < SRC; ++t) {
        const float* hin = hbuf[t & 1];
        float* hout = hbuf[(t + 1) & 1];
        // stage h[32][512] via 8B bypass loads -> chunk-padded LDS
        const unsigned long long* hin8 = (const unsigned long long*)hin;
        for (int idx = tid; idx < 32 * 256; idx += 512) {
            unsigned long long uv = __hip_atomic_load(&hin8[idx], __ATOMIC_RELAXED,
                                                      __HIP_MEMORY_SCOPE_AGENT);
            union { unsigned long long u; float f[2]; } cv; cv.u = uv;
            int nn = idx >> 8, kk = (idx & 255) << 1;
            int off = nn * 576 + (kk >> 5) * 36 + (kk & 31);
            hlds[off] = cv.f[0];
            hlds[off + 1] = cv.f[1];
        }
        __syncthreads();

        float aR[4] = {0.f, 0.f, 0.f, 0.f};
        float aZ[4] = {0.f, 0.f, 0.f, 0.f};
        float aN[4] = {0.f, 0.f, 0.f, 0.f};
        const float* h0p = &hlds[(ng * 4 + 0) * 576 + kbase];
        const float* h1p = &hlds[(ng * 4 + 1) * 576 + kbase];
        const float* h2p = &hlds[(ng * 4 + 2) * 576 + kbase];
        const float* h3p = &hlds[(ng * 4 + 3) * 576 + kbase];
#pragma unroll
        for (int i = 0; i < 8; ++i) {
            float4 wr = wreg[0][i], wz = wreg[1][i], wn = wreg[2][i];
            float4 ha = *(const float4*)&h0p[i * 4];
            float4 hb = *(const float4*)&h1p[i * 4];
            float4 hc = *(const float4*)&h2p[i * 4];
            float4 hd = *(const float4*)&h3p[i * 4];
            aR[0] += ha.x*wr.x + ha.y*wr.y + ha.z*wr.z + ha.w*wr.w;
            aZ[0] += ha.x*wz.x + ha.y*wz.y + ha.z*wz.z + ha.w*wz.w;
            aN[0] += ha.x*wn.x + ha.y*wn.y + ha.z*wn.z + ha.w*wn.w;
            aR[1] += hb.x*wr.x + hb.y*wr.y + hb.z*wr.z + hb.w*wr.w;
            aZ[1] += hb.x*wz.x + hb.y*wz.y + hb.z*wz.z + hb.w*wz.w;
            aN[1] += hb.x*wn.x + hb.y*wn.y + hb.z*wn.z + hb.w*wn.w;
            aR[2] += hc.x*wr.x + hc.y*wr.y + hc.z*wr.z + hc.w*wr.w;
            aZ[2] += hc.x*wz.x + hc.y*wz.y + hc.z*wz.z + hc.w*wz.w;
            aN[2] += hc.x*wn.x + hc.y*wn.y + hc.z*wn.z + hc.w*wn.w;
            aR[3] += hd.x*wr.x + hd.y*wr.y + hd.z*wr.z + hd.w*wr.w;
            aZ[3] += hd.x*wz.x + hd.y*wz.y + hd.z*wz.z + hd.w*wz.w;
            aN[3] += hd.x*wn.x + hd.y*wn.y + hd.z*wn.z + hd.w*wn.w;
        }
        // reduce over kh (lane bits 2..5)
#pragma unroll
        for (int r = 0; r < 4; ++r) {
            aR[r] += __shfl_xor(aR[r], 4);  aR[r] += __shfl_xor(aR[r], 8);
            aR[r] += __shfl_xor(aR[r], 16); aR[r] += __shfl_xor(aR[r], 32);
            aZ[r] += __shfl_xor(aZ[r], 4);  aZ[r] += __shfl_xor(aZ[r], 8);
            aZ[r] += __shfl_xor(aZ[r], 16); aZ[r] += __shfl_xor(aZ[r], 32);
            aN[r] += __shfl_xor(aN[r], 4);  aN[r] += __shfl_xor(aN[r], 8);
            aN[r] += __shfl_xor(aN[r], 16); aN[r] += __shfl_xor(aN[r], 32);
        }
        if (kh == 0) {
            int s = z ? (SRC - 1 - t) : t;
#pragma unroll
            for (int r = 0; r < 4; ++r) {
                int n = ng * 4 + r;
                const float* gir = gi + (size_t)(s * NB + n) * G3;
                float rr  = sigmf(gir[j] + bR + aR[r]);
                float zz  = sigmf(gir[512 + j] + bZ + aZ[r]);
                float nn2 = tanhf(gir[1024 + j] + bN + rr * aN[r]);
                float hp  = hlds[n * 576 + (j >> 5) * 36 + (j & 31)];
                float hnew = (1.f - zz) * nn2 + zz * hp;
                __hip_atomic_store(&hout[n * 512 + j], hnew, __ATOMIC_RELAXED,
                                   __HIP_MEMORY_SCOPE_AGENT);
                enc[(size_t)(n * SRC + s) * 1024 + z * 512 + j] = hnew;
            }
        }
        __syncthreads();   // drains vmcnt(0) per wave -> all stores at coherence point
        if (tid == 0) {
            __hip_atomic_fetch_add(&cntd[t], 1u, __ATOMIC_RELAXED, __HIP_MEMORY_SCOPE_AGENT);
            while (__hip_atomic_load(&cntd[t], __ATOMIC_RELAXED, __HIP_MEMORY_SCOPE_AGENT)
                   < (unsigned)ENC_PER_DIR)
                __builtin_amdgcn_s_sleep(2);
        }
        __syncthreads();
    }
}

// ---------------- persistent decoder recurrence (same pattern, 1 dir, 30 steps) ----
__global__ __launch_bounds__(512) void dec_scan_kernel(
    const float* __restrict__ gi, const float* __restrict__ Whh,
    const float* __restrict__ bhh, const float* __restrict__ h0,
    float* __restrict__ hall, unsigned int* __restrict__ cnt) {
    const int j0 = blockIdx.x * 4;
    __shared__ float hlds[32 * 576];
    const int tid = threadIdx.x;
    const int jl = tid & 3;
    const int kh = (tid >> 2) & 15;
    const int ng = tid >> 6;
    const int j  = j0 + jl;
    const int kbase = kh * 36;

    float4 wreg[3][8];
#pragma unroll
    for (int g = 0; g < 3; ++g) {
        const float* wp = Whh + (size_t)(g * 512 + j) * 512 + kh * 32;
#pragma unroll
        for (int i = 0; i < 8; ++i) wreg[g][i] = *(const float4*)&wp[i * 4];
    }
    const float bR = bhh[j], bZ = bhh[512 + j], bN = bhh[1024 + j];

    for (int t = 0; t < TDD; ++t) {
        const float* hin = t ? (hall + (size_t)(t - 1) * NB * 512) : h0;
        float* hout = hall + (size_t)t * NB * 512;
        const unsigned long long* hin8 = (const unsigned long long*)hin;
        for (int idx = tid; idx < 32 * 256; idx += 512) {
            unsigned long long uv = __hip_atomic_load(&hin8[idx], __ATOMIC_RELAXED,
                                                      __HIP_MEMORY_SCOPE_AGENT);
            union { unsigned long long u; float f[2]; } cv; cv.u = uv;
            int nn = idx >> 8, kk = (idx & 255) << 1;
            int off = nn * 576 + (kk >> 5) * 36 + (kk & 31);
            hlds[off] = cv.f[0];
            hlds[off + 1] = cv.f[1];
        }
        __syncthreads();

        float aR[4] = {0.f, 0.f, 0.f, 0.f};
        float aZ[4] = {0.f, 0.f, 0.f, 0.f};
        float aN[4] = {0.f, 0.f, 0.f, 0.f};
        const float* h0p = &hlds[(ng * 4 + 0) * 576 + kbase];
        const float* h1p = &hlds[(ng * 4 + 1) * 576 + kbase];
        const float* h2p = &hlds[(ng * 4 + 2) * 576 + kbase];
        const float* h3p = &hlds[(ng * 4 + 3) * 576 + kbase];
#pragma unroll
        for (int i = 0; i < 8; ++i) {
            float4 wr = wreg[0][i], wz = wreg[1][i], wn = wreg[2][i];
            float4 ha = *(const float4*)&h0p[i * 4];
            float4 hb = *(const float4*)&h1p[i * 4];
            float4 hc = *(const float4*)&h2p[i * 4];
            float4 hd = *(const float4*)&h3p[i * 4];
            aR[0] += ha.x*wr.x + ha.y*wr.y + ha.z*wr.z + ha.w*wr.w;
            aZ[0] += ha.x*wz.x + ha.y*wz.y + ha.z*wz.z + ha.w*wz.w;
            aN[0] += ha.x*wn.x + ha.y*wn.y + ha.z*wn.z + ha.w*wn.w;
            aR[1] += hb.x*wr.x + hb.y*wr.y + hb.z*wr.z + hb.w*wr.w;
            aZ[1] += hb.x*wz.x + hb.y*wz.y + hb.z*wz.z + hb.w*wz.w;
            aN[1] += hb.x*wn.x + hb.y*wn.y + hb.z*wn.z + hb.w*wn.w;
            aR[2] += hc.x*wr.x + hc.y*wr.y + hc.z*wr.z + hc.w*wr.w;
            aZ[2] += hc.x*wz.x + hc.y*wz.y + hc.z*wz.z + hc.w*wz.w;
            aN[2] += hc.x*wn.x + hc.y*wn.y + hc.z*wn.z + hc.w*wn.w;
            aR[3] += hd.x*wr.x + hd.y*wr.y + hd.z*wr.z + hd.w*wr.w;
            aZ[3] += hd.x*wz.x + hd.y*wz.y + hd.z*wz.z + hd.w*wz.w;
            aN[3] += hd.x*wn.x + hd.y*wn.y + hd.z*wn.z + hd.w*wn.w;
        }
#pragma unroll
        for (int r = 0; r < 4; ++r) {
            aR[r] += __shfl_xor(aR[r], 4);  aR[r] += __shfl_xor(aR[r], 8);
            aR[r] += __shfl_xor(aR[r], 16); aR[r] += __shfl_xor(aR[r], 32);
            aZ[r] += __shfl_xor(aZ[r], 4);  aZ[r] += __shfl_xor(aZ[r], 8);
            aZ[r] += __shfl_xor(aZ[r], 16); aZ[r] += __shfl_xor(aZ[r], 32);
            aN[r] += __shfl_xor(aN[r], 4);  aN[r] += __shfl_xor(aN[r], 8);
            aN[r] += __shfl_xor(aN[r], 16); aN[r] += __shfl_xor(aN[r], 32);
        }
        if (kh == 0) {
#pragma unroll
            for (int r = 0; r < 4; ++r) {
                int n = ng * 4 + r;
                const float* gir = gi + (size_t)(t * NB + n) * G3;
                float rr  = sigmf(gir[j] + bR + aR[r]);
                float zz  = sigmf(gir[512 + j] + bZ + aZ[r]);
                float nn2 = tanhf(gir[1024 + j] + bN + rr * aN[r]);
                float hp  = hlds[n * 576 + (j >> 5) * 36 + (j & 31)];
                float hnew = (1.f - zz) * nn2 + zz * hp;
                __hip_atomic_store(&hout[n * 512 + j], hnew, __ATOMIC_RELAXED,
                                   __HIP_MEMORY_SCOPE_AGENT);
            }
        }
        __syncthreads();
        if (tid == 0) {
            __hip_atomic_fetch_add(&cnt[t], 1u, __ATOMIC_RELAXED, __HIP_MEMORY_SCOPE_AGENT);
            while (__hip_atomic_load(&cnt[t], __ATOMIC_RELAXED, __HIP_MEMORY_SCOPE_AGENT)
                   < (unsigned)DEC_NBLK)
                __builtin_amdgcn_s_sleep(2);
        }
        __syncthreads();
    }
}

// key_proj: kp[(n*SRC+s)*512 + c] = sum_k enc[row][k]*Wk[k*512+c]. 8 rows/block.
__global__ __launch_bounds__(256) void keyproj_kernel(const float* __restrict__ enc,
                                                      const float* __restrict__ Wk,
                                                      float* __restrict__ kp) {
    __shared__ float sx[8][1024];
    int tid = threadIdx.x;
    int g0 = blockIdx.x * 8;
    for (int i = tid; i < 8 * 1024; i += 256)
        sx[i >> 10][i & 1023] = enc[(size_t)(g0 + (i >> 10)) * 1024 + (i & 1023)];
    __syncthreads();
    int c = blockIdx.y * 256 + tid;
    float acc[8];
#pragma unroll
    for (int r = 0; r < 8; ++r) acc[r] = 0.f;
    for (int k = 0; k < 1024; k += 4) {
        float w0 = Wk[(size_t)(k + 0) * 512 + c];
        float w1 = Wk[(size_t)(k + 1) * 512 + c];
        float w2 = Wk[(size_t)(k + 2) * 512 + c];
        float w3 = Wk[(size_t)(k + 3) * 512 + c];
#pragma unroll
        for (int r = 0; r < 8; ++r) {
            float4 x4 = *(const float4*)&sx[r][k];
            acc[r] += x4.x * w0 + x4.y * w1 + x4.z * w2 + x4.w * w3;
        }
    }
#pragma unroll
    for (int r = 0; r < 8; ++r) kp[(size_t)(g0 + r) * 512 + c] = acc[r];
}

// q_all[tn][c] = battn[c] + hD_all[tn] . Wd[:,c]; 8 rows/block, grid (120,2)
__global__ __launch_bounds__(256) void qall_kernel(const float* __restrict__ hall,
                                                   const float* __restrict__ Wd,
                                                   const float* __restrict__ battn,
                                                   float* __restrict__ qall) {
    __shared__ float sx[8][512];
    int tid = threadIdx.x;
    int g0 = blockIdx.x * 8;
    for (int i = tid; i < 8 * 512; i += 256)
        sx[i >> 9][i & 511] = hall[(size_t)(g0 + (i >> 9)) * 512 + (i & 511)];
    __syncthreads();
    int c = blockIdx.y * 256 + tid;
    float b = battn[c];
    float acc[8];
#pragma unroll
    for (int r = 0; r < 8; ++r) acc[r] = b;
    for (int k = 0; k < 512; k += 4) {
        float w0 = Wd[(size_t)(k + 0) * 512 + c];
        float w1 = Wd[(size_t)(k + 1) * 512 + c];
        float w2 = Wd[(size_t)(k + 2) * 512 + c];
        float w3 = Wd[(size_t)(k + 3) * 512 + c];
#pragma unroll
        for (int r = 0; r < 8; ++r) {
            float4 x4 = *(const float4*)&sx[r][k];
            acc[r] += x4.x * w0 + x4.y * w1 + x4.z * w2 + x4.w * w3;
        }
    }
#pragma unroll
    for (int r = 0; r < 8; ++r) qall[(size_t)(g0 + r) * 512 + c] = acc[r];
}

// e_all[(tn)*SRC+s] = v . tanh(kp[n,s,:] + q_all[tn]) + mask ; 4 rows/block
__global__ __launch_bounds__(256) void escoreall_kernel(const float* __restrict__ kp,
                                                        const float* __restrict__ qall,
                                                        const float* __restrict__ vvec,
                                                        const float* __restrict__ mask,
                                                        float* __restrict__ e) {
    __shared__ float sq[512];
    int tid = threadIdx.x;
    int row0 = blockIdx.x * 4;
    int tn = row0 / SRC;    // 4 | SRC so all 4 rows share tn
    int n = tn % NB;
    sq[tid] = qall[(size_t)tn * 512 + tid];
    sq[256 + tid] = qall[(size_t)tn * 512 + 256 + tid];
    __syncthreads();
    int w = tid >> 6, lane = tid & 63;
    int row = row0 + w;
    int s = row % SRC;
    const float* kpr = kp + (size_t)(n * SRC + s) * 512;
    float acc = 0.f;
#pragma unroll
    for (int i = 0; i < 8; ++i) {
        int d = lane + i * 64;
        acc += vvec[d] * tanhf(kpr[d] + sq[d]);
    }
    for (int off = 32; off; off >>= 1) acc += __shfl_down(acc, off, 64);
    if (lane == 0) e[row] = acc + (1.f - mask[n * SRC + s]) * (-1e10f);
}

// softmax over SRC per row, in place. block per row.
__global__ __launch_bounds__(256) void softmaxS_kernel(float* __restrict__ e) {
    __shared__ float red[256];
    int n = blockIdx.x, tid = threadIdx.x;
    float* row = e + (size_t)n * SRC;
    float m = -3.4e38f;
    for (int s = tid; s < SRC; s += 256) m = fmaxf(m, row[s]);
    red[tid] = m; __syncthreads();
    for (int off = 128; off; off >>= 1) { if (tid < off) red[tid] = fmaxf(red[tid], red[tid + off]); __syncthreads(); }
    m = red[0]; __syncthreads();
    float sum = 0.f;
    for (int s = tid; s < SRC; s += 256) sum += expf(row[s] - m);
    red[tid] = sum; __syncthreads();
    for (int off = 128; off; off >>= 1) { if (tid < off) red[tid] += red[tid + off]; __syncthreads(); }
    float inv = 1.f / red[0]; __syncthreads();
    for (int s = tid; s < SRC; s += 256) row[s] = expf(row[s] - m) * inv;
}

// ctx_all[(t*NB+n)*1024+d] = sum_s attn[(t*NB+n)*SRC+s]*enc[n,s,d]; grid (32,4)
__global__ __launch_bounds__(256) void ctxall_kernel(const float* __restrict__ attn,
                                                     const float* __restrict__ enc,
                                                     float* __restrict__ ctxall) {
    __shared__ float sa[TDD * SRC];   // 48 KB
    int n = blockIdx.x, tid = threadIdx.x;
    for (int i = tid; i < TDD * SRC; i += 256) {
        int t = i / SRC, s = i - t * SRC;
        sa[i] = attn[(size_t)(t * NB + n) * SRC + s];
    }
    __syncthreads();
    int d = blockIdx.y * 256 + tid;
    const float* er = enc + (size_t)n * SRC * 1024 + d;
    float acc[TDD];
#pragma unroll
    for (int t = 0; t < TDD; ++t) acc[t] = 0.f;
    for (int s = 0; s < SRC; s += 4) {
        float e0 = er[(size_t)(s + 0) * 1024];
        float e1 = er[(size_t)(s + 1) * 1024];
        float e2 = er[(size_t)(s + 2) * 1024];
        float e3 = er[(size_t)(s + 3) * 1024];
#pragma unroll
        for (int t = 0; t < TDD; ++t) {
            float4 a4 = *(const float4*)&sa[t * SRC + s];
            acc[t] += a4.x * e0 + a4.y * e1 + a4.z * e2 + a4.w * e3;
        }
    }
#pragma unroll
    for (int t = 0; t < TDD; ++t) ctxall[(size_t)(t * NB + n) * 1024 + d] = acc[t];
}

// pgen_all[tn] = sigmoid([xi, ctx, h] . Wp + bp); block per tn, grid 960
__global__ __launch_bounds__(256) void pgenall_kernel(const int* __restrict__ trg_ids,
                                                      const float* __restrict__ embed,
                                                      const float* __restrict__ ctxall,
                                                      const float* __restrict__ hall,
                                                      const float* __restrict__ Wp,
                                                      const float* __restrict__ bp,
                                                      float* __restrict__ pgenall) {
    __shared__ float red[256];
    int tn = blockIdx.x, tid = threadIdx.x;
    int t = tn / NB, n = tn % NB;
    int tok = trg_ids[n * TDD + t];
    float acc = 0.f;
    for (int i = tid; i < 1792; i += 256) {
        float val;
        if (i < 256) val = embed[(size_t)tok * EMB + i];
        else if (i < 1280) val = ctxall[(size_t)tn * 1024 + (i - 256)];
        else val = hall[(size_t)tn * 512 + (i - 1280)];
        acc += val * Wp[i];
    }
    red[tid] = acc; __syncthreads();
    for (int off = 128; off; off >>= 1) { if (tid < off) red[tid] += red[tid + off]; __syncthreads(); }
    if (tid == 0) pgenall[tn] = 1.f / (1.f + expf(-(red[0] + bp[0])));
}

// hid1_all[tn][c] = b1[c] + [h,ctx] . W1[:,c]; 8 rows/block, grid (120,2)
__global__ __launch_bounds__(256) void hid1all_kernel(const float* __restrict__ hall,
                                                      const float* __restrict__ ctxall,
                                                      const float* __restrict__ W1,
                                                      const float* __restrict__ b1,
                                                      float* __restrict__ hid1all) {
    __shared__ float sc[8][1536];   // 48 KB
    int tid = threadIdx.x;
    int g0 = blockIdx.x * 8;
    for (int i = tid; i < 8 * 512; i += 256)
        sc[i >> 9][i & 511] = hall[(size_t)(g0 + (i >> 9)) * 512 + (i & 511)];
    for (int i = tid; i < 8 * 1024; i += 256)
        sc[i >> 10][512 + (i & 1023)] = ctxall[(size_t)(g0 + (i >> 10)) * 1024 + (i & 1023)];
    __syncthreads();
    int c = blockIdx.y * 256 + tid;
    float acc[8];
    float b = b1[c];
#pragma unroll
    for (int r = 0; r < 8; ++r) acc[r] = b;
    for (int k = 0; k < 1536; k += 4) {
        float w0 = W1[(size_t)(k + 0) * 512 + c];
        float w1 = W1[(size_t)(k + 1) * 512 + c];
        float w2 = W1[(size_t)(k + 2) * 512 + c];
        float w3 = W1[(size_t)(k + 3) * 512 + c];
#pragma unroll
        for (int r = 0; r < 8; ++r) {
            float4 x4 = *(const float4*)&sc[r][k];
            acc[r] += x4.x * w0 + x4.y * w1 + x4.z * w2 + x4.w * w3;
        }
    }
#pragma unroll
    for (int r = 0; r < 8; ++r) hid1all[(size_t)(g0 + r) * 512 + c] = acc[r];
}

// logits_all: 32-row groups; grid (196, 30). thread per j, 32 rows in registers.
__global__ __launch_bounds__(256) void logitsall_kernel(const float* __restrict__ hid1,
                                                        const float* __restrict__ W2,
                                                        const float* __restrict__ b2,
                                                        float* __restrict__ logits) {
    __shared__ float sh[32][512];   // 64 KB
    int tid = threadIdx.x;
    int r0 = blockIdx.y * 32;
    for (int i = tid; i < 32 * 512; i += 256) sh[i >> 9][i & 511] = hid1[(size_t)r0 * 512 + i];
    __syncthreads();
    int j = blockIdx.x * 256 + tid;
    if (j >= VSZ) return;
    float acc[32];
#pragma unroll
    for (int r = 0; r < 32; ++r) acc[r] = 0.f;
    for (int k = 0; k < 512; k += 4) {
        float w0 = W2[(size_t)(k + 0) * VSZ + j];
        float w1 = W2[(size_t)(k + 1) * VSZ + j];
        float w2 = W2[(size_t)(k + 2) * VSZ + j];
        float w3 = W2[(size_t)(k + 3) * VSZ + j];
#pragma unroll
        for (int r = 0; r < 32; ++r) {
            float4 h4 = *(const float4*)&sh[r][k];
            acc[r] += h4.x * w0 + h4.y * w1 + h4.z * w2 + h4.w * w3;
        }
    }
    float bb = b2[j];
#pragma unroll
    for (int r = 0; r < 32; ++r) logits[(size_t)(r0 + r) * VSZ + j] = acc[r] + bb;
}

// softmax over V, scale by p_gen, write out row; block per tn
__global__ __launch_bounds__(1024) void outall_kernel(const float* __restrict__ logits,
                                                      const float* __restrict__ pgenall,
                                                      float* __restrict__ out) {
    __shared__ float red[1024];
    int tn = blockIdx.x, tid = threadIdx.x;
    int t = tn / NB, n = tn % NB;
    const float* lrow = logits + (size_t)tn * VSZ;
    float m = -3.4e38f;
    for (int j = tid; j < VSZ; j += 1024) m = fmaxf(m, lrow[j]);
    red[tid] = m; __syncthreads();
    for (int off = 512; off; off >>= 1) { if (tid < off) red[tid] = fmaxf(red[tid], red[tid + off]); __syncthreads(); }
    m = red[0]; __syncthreads();
    float sum = 0.f;
    for (int j = tid; j < VSZ; j += 1024) sum += expf(lrow[j] - m);
    red[tid] = sum; __syncthreads();
    for (int off = 512; off; off >>= 1) { if (tid < off) red[tid] += red[tid + off]; __syncthreads(); }
    float inv = pgenall[tn] / red[0];
    float* orow = out + (size_t)(n * TDD + t) * VE;
    for (int j = tid; j < VE; j += 1024) orow[j] = (j < VSZ) ? expf(lrow[j] - m) * inv : 0.f;
}

// out[n, t, ptr[n,s]] += (1-p_gen[tn]) * attn[tn,s] for all t,n,s
__global__ __launch_bounds__(256) void scatterall_kernel(const int* __restrict__ ptr,
                                                         const float* __restrict__ attn,
                                                         const float* __restrict__ pgenall,
                                                         float* __restrict__ out) {
    int f = blockIdx.x * 256 + threadIdx.x;
    if (f >= TDD * NB * SRC) return;
    int tn = f / SRC;
    int s = f - tn * SRC;
    int t = tn / NB, n = tn % NB;
    float w = (1.f - pgenall[tn]) * attn[f];
    atomicAdd(&out[(size_t)(n * TDD + t) * VE + ptr[n * SRC + s]], w);
}

extern "C" void kernel_launch(void* const* d_in, const int* in_sizes, int n_in,
                              void* d_out, int out_size, void* d_ws, size_t ws_size,
                              hipStream_t stream) {
    const int*   src_ids  = (const int*)d_in[0];
    const float* src_mask = (const float*)d_in[1];
    const int*   trg_ids  = (const int*)d_in[2];
    const int*   ptr_idx  = (const int*)d_in[3];
    const float* embed    = (const float*)d_in[4];
    const float* Wih_f = (const float*)d_in[5];
    const float* Whh_f = (const float*)d_in[6];
    const float* bih_f = (const float*)d_in[7];
    const float* bhh_f = (const float*)d_in[8];
    const float* Wih_b = (const float*)d_in[9];
    const float* Whh_b = (const float*)d_in[10];
    const float* bih_b = (const float*)d_in[11];
    const float* bhh_b = (const float*)d_in[12];
    const float* Wih_d = (const float*)d_in[13];
    const float* Whh_d = (const float*)d_in[14];
    const float* bih_d = (const float*)d_in[15];
    const float* bhh_d = (const float*)d_in[16];
    const float* Wk    = (const float*)d_in[17];
    const float* Wd    = (const float*)d_in[18];
    const float* battn = (const float*)d_in[19];
    const float* vvec  = (const float*)d_in[20];
    const float* W1    = (const float*)d_in[21];
    const float* b1    = (const float*)d_in[22];
    const float* W2    = (const float*)d_in[23];
    const float* b2    = (const float*)d_in[24];
    const float* Wp    = (const float*)d_in[25];
    const float* bp    = (const float*)d_in[26];
    float* out = (float*)d_out;

    float* w = (float*)d_ws;
    float* WihTf = w; w += 256 * G3;
    float* WihTb = w; w += 256 * G3;
    float* WihTd = w; w += 256 * G3;
    float* giF = w; w += (size_t)SRC * NB * G3;   // dead after enc_scan
    float* giB = w; w += (size_t)SRC * NB * G3;   // dead after enc_scan
    float* giD = w; w += (size_t)TDD * NB * G3;   // dead after dec_scan
    float* enc = w; w += (size_t)NB * SRC * 1024; // dead after ctx_all
    float* kp  = w; w += (size_t)NB * SRC * 512;  // dead after escore_all
    float* hF0 = w; w += NB * HE;
    float* hF1 = w; w += NB * HE;
    float* hB0 = w; w += NB * HE;
    float* hB1 = w; w += NB * HE;
    float* h0d = w; w += NB * HD;
    float* hD_all = w; w += (size_t)TDD * NB * HD;
    float* q_all  = w; w += (size_t)TDD * NB * 512;
    float* e_all  = w; w += (size_t)TDD * NB * SRC;
    float* ctx_all = w; w += (size_t)TDD * NB * 1024;
    float* hid1_all = w; w += (size_t)TDD * NB * 512;
    float* pgen_all = w; w += 1024;
    unsigned int* cnt = (unsigned int*)w; w += 2048;
    // logits_all (960*50000 = 48M floats) aliases giF..enc-prefix (dead by then)
    float* logits_all = giF;

    // ---- weight transposes (WihT x3 for gi) ----
    transpose_kernel<<<(G3 * 256 + 255) / 256, 256, 0, stream>>>(Wih_f, WihTf, G3, 256);
    transpose_kernel<<<(G3 * 256 + 255) / 256, 256, 0, stream>>>(Wih_b, WihTb, G3, 256);
    transpose_kernel<<<(G3 * 256 + 255) / 256, 256, 0, stream>>>(Wih_d, WihTd, G3, 256);

    // ---- input-gate precompute ----
    gi_kernel<<<dim3(SRC * NB / 16, 6), 256, 0, stream>>>(src_ids, embed, WihTf, bih_f, giF, SRC);
    gi_kernel<<<dim3(SRC * NB / 16, 6), 256, 0, stream>>>(src_ids, embed, WihTb, bih_b, giB, SRC);
    gi_kernel<<<dim3(TDD * NB / 16, 6), 256, 0, stream>>>(trg_ids, embed, WihTd, bih_d, giD, TDD);

    hipMemsetAsync(hF0, 0, NB * HE * sizeof(float), stream);
    hipMemsetAsync(hB0, 0, NB * HE * sizeof(float), stream);
    hipMemsetAsync(h0d, 0, NB * HD * sizeof(float), stream);
    hipMemsetAsync(cnt, 0, 2048 * sizeof(unsigned int), stream);

    // ---- encoder scan: persistent, L2-bypass software barrier ----
    enc_scan_kernel<<<2 * ENC_PER_DIR, 512, 0, stream>>>(
        giF, giB, Whh_f, Whh_b, bhh_f, bhh_b,
        hF0, hF1, hB0, hB1, enc, cnt);

    keyproj_kernel<<<dim3(NB * SRC / 8, 2), 256, 0, stream>>>(enc, Wk, kp);

    // ---- decoder recurrence: persistent (30 steps, 128 blocks) ----
    dec_scan_kernel<<<DEC_NBLK, 512, 0, stream>>>(giD, Whh_d, bhh_d, h0d, hD_all, cnt + 1024);

    // ---- fully batched decoder head over all 30 steps ----
    qall_kernel<<<dim3(TDD * NB / 8, 2), 256, 0, stream>>>(hD_all, Wd, battn, q_all);
    escoreall_kernel<<<TDD * NB * SRC / 4, 256, 0, stream>>>(kp, q_all, vvec, src_mask, e_all);
    softmaxS_kernel<<<TDD * NB, 256, 0, stream>>>(e_all);
    ctxall_kernel<<<dim3(NB, 4), 256, 0, stream>>>(e_all, enc, ctx_all);
    pgenall_kernel<<<TDD * NB, 256, 0, stream>>>(trg_ids, embed, ctx_all, hD_all, Wp, bp, pgen_all);
    hid1all_kernel<<<dim3(TDD * NB / 8, 2), 256, 0, stream>>>(hD_all, ctx_all, W1, b1, hid1_all);
    logitsall_kernel<<<dim3((VSZ + 255) / 256, TDD), 256, 0, stream>>>(hid1_all, W2, b2, logits_all);
    outall_kernel<<<TDD * NB, 1024, 0, stream>>>(logits_all, pgen_all, out);
    scatterall_kernel<<<(TDD * NB * SRC + 255) / 256, 256, 0, stream>>>(ptr_idx, e_all, pgen_all, out);
}

// Round 4
// 7686.725 us; speedup vs baseline: 2.2113x; 1.1362x over previous
//
#include <hip/hip_runtime.h>
#include <math.h>

#define VSZ 50000
#define OOVN 50
#define VE 50050
#define EMB 256
#define HE 512
#define HD 512
#define NB 32
#define SRC 400
#define TDD 30
#define G3 1536   // 3*HE = 3*HD
#define ENC_PER_DIR 128
#define DEC_NBLK 128

__device__ __forceinline__ float sigmf(float x) { return 1.f / (1.f + expf(-x)); }

// out[c*rows + r] = in[r*cols + c]
__global__ __launch_bounds__(256) void transpose_kernel(const float* __restrict__ in,
                                                        float* __restrict__ out,
                                                        int rows, int cols) {
    int idx = blockIdx.x * 256 + threadIdx.x;
    if (idx >= rows * cols) return;
    int r = idx / cols, c = idx % cols;
    out[c * rows + r] = in[idx];
}

// gi[(s*NB+n)*G3 + c] = bih[c] + sum_e embed[ids[n*steps+s]][e] * WihT[e*G3+c]
__global__ __launch_bounds__(256) void gi_kernel(const int* __restrict__ ids,
                                                 const float* __restrict__ embed,
                                                 const float* __restrict__ WihT,
                                                 const float* __restrict__ bih,
                                                 float* __restrict__ gi, int steps) {
    __shared__ float sx[16][EMB];
    __shared__ int stok[16];
    int tid = threadIdx.x;
    int g0 = blockIdx.x * 16;
    if (tid < 16) {
        int row = g0 + tid;
        int s = row / NB, n = row % NB;
        stok[tid] = ids[n * steps + s];
    }
    __syncthreads();
    for (int r = 0; r < 16; ++r) sx[r][tid] = embed[(size_t)stok[r] * EMB + tid];
    __syncthreads();
    int c = blockIdx.y * 256 + tid;
    float b = bih[c];
    float acc[16];
#pragma unroll
    for (int r = 0; r < 16; ++r) acc[r] = b;
    for (int e = 0; e < EMB; e += 4) {
        float w0 = WihT[(size_t)(e + 0) * G3 + c];
        float w1 = WihT[(size_t)(e + 1) * G3 + c];
        float w2 = WihT[(size_t)(e + 2) * G3 + c];
        float w3 = WihT[(size_t)(e + 3) * G3 + c];
#pragma unroll
        for (int r = 0; r < 16; ++r) {
            float4 x4 = *(const float4*)&sx[r][e];
            acc[r] += x4.x * w0 + x4.y * w1 + x4.z * w2 + x4.w * w3;
        }
    }
#pragma unroll
    for (int r = 0; r < 16; ++r) gi[(size_t)(g0 + r) * G3 + c] = acc[r];
}

// ---------------- persistent encoder scan, flag-array barrier (no RMW) --------
// grid 256: bid>>7 = dir, (bid&127)*4 = j0. 512 threads: jl=tid&3, kh=(tid>>2)&15,
// ng=tid>>6 (4 n each). Weights in registers. h exchanged via agent-scope
// write-through stores + bypass loads. Barrier: per-block flag store + wave-0
// poll of 128 flags (2 loads/lane + __all) -- no atomic RMW, no same-line ping-pong.
__global__ __launch_bounds__(512) void enc_scan_kernel(
    const float* __restrict__ giF, const float* __restrict__ giB,
    const float* __restrict__ WhhF, const float* __restrict__ WhhB,
    const float* __restrict__ bhhF, const float* __restrict__ bhhB,
    float* __restrict__ hF0, float* __restrict__ hF1,
    float* __restrict__ hB0, float* __restrict__ hB1,
    float* __restrict__ enc, unsigned int* __restrict__ flags) {
    const int bid = blockIdx.x;
    const int z = bid >> 7;
    const int b1 = bid & 127;
    const int j0 = b1 * 4;
    const float* gi  = z ? giB : giF;
    const float* Whh = z ? WhhB : WhhF;
    const float* bhh = z ? bhhB : bhhF;
    float* hbuf[2];
    hbuf[0] = z ? hB0 : hF0;
    hbuf[1] = z ? hB1 : hF1;
    unsigned int* fl = flags + (size_t)z * SRC * 128;

    __shared__ float hlds[32 * 576];   // [n][kh*36 + i]  73.7 KB

    const int tid = threadIdx.x;
    const int jl = tid & 3;
    const int kh = (tid >> 2) & 15;
    const int ng = tid >> 6;
    const int j  = j0 + jl;
    const int kbase = kh * 36;

    // ---- weights to registers: 3 gates x 8 float4 (k-chunk of 32) ----
    float4 wreg[3][8];
#pragma unroll
    for (int g = 0; g < 3; ++g) {
        const float* wp = Whh + (size_t)(g * 512 + j) * 512 + kh * 32;
#pragma unroll
        for (int i = 0; i < 8; ++i) wreg[g][i] = *(const float4*)&wp[i * 4];
    }
    const float bR = bhh[j], bZ = bhh[512 + j], bN = bhh[1024 + j];

    for (int t = 0; t < SRC; ++t) {
        const float* hin = hbuf[t & 1];
        float* hout = hbuf[(t + 1) & 1];
        const int s = z ? (SRC - 1 - t) : t;

        // ---- gi prefetch (issued early; latency hides under staging+compute) ----
        float gpre[12];
        if (kh == 0) {
#pragma unroll
            for (int r = 0; r < 4; ++r) {
                const float* gir = gi + (size_t)(s * NB + ng * 4 + r) * G3 + j;
                gpre[r * 3 + 0] = gir[0];
                gpre[r * 3 + 1] = gir[512];
                gpre[r * 3 + 2] = gir[1024];
            }
        }

        // stage h[32][512] via 8B bypass loads -> chunk-padded LDS
        const unsigned long long* hin8 = (const unsigned long long*)hin;
        for (int idx = tid; idx < 32 * 256; idx += 512) {
            unsigned long long uv = __hip_atomic_load(&hin8[idx], __ATOMIC_RELAXED,
                                                      __HIP_MEMORY_SCOPE_AGENT);
            union { unsigned long long u; float f[2]; } cv; cv.u = uv;
            int nn = idx >> 8, kk = (idx & 255) << 1;
            int off = nn * 576 + (kk >> 5) * 36 + (kk & 31);
            hlds[off] = cv.f[0];
            hlds[off + 1] = cv.f[1];
        }
        __syncthreads();

        float aR[4] = {0.f, 0.f, 0.f, 0.f};
        float aZ[4] = {0.f, 0.f, 0.f, 0.f};
        float aN[4] = {0.f, 0.f, 0.f, 0.f};
        const float* h0p = &hlds[(ng * 4 + 0) * 576 + kbase];
        const float* h1p = &hlds[(ng * 4 + 1) * 576 + kbase];
        const float* h2p = &hlds[(ng * 4 + 2) * 576 + kbase];
        const float* h3p = &hlds[(ng * 4 + 3) * 576 + kbase];
#pragma unroll
        for (int i = 0; i < 8; ++i) {
            float4 wr = wreg[0][i], wz = wreg[1][i], wn = wreg[2][i];
            float4 ha = *(const float4*)&h0p[i * 4];
            float4 hb = *(const float4*)&h1p[i * 4];
            float4 hc = *(const float4*)&h2p[i * 4];
            float4 hd = *(const float4*)&h3p[i * 4];
            aR[0] += ha.x*wr.x + ha.y*wr.y + ha.z*wr.z + ha.w*wr.w;
            aZ[0] += ha.x*wz.x + ha.y*wz.y + ha.z*wz.z + ha.w*wz.w;
            aN[0] += ha.x*wn.x + ha.y*wn.y + ha.z*wn.z + ha.w*wn.w;
            aR[1] += hb.x*wr.x + hb.y*wr.y + hb.z*wr.z + hb.w*wr.w;
            aZ[1] += hb.x*wz.x + hb.y*wz.y + hb.z*wz.z + hb.w*wz.w;
            aN[1] += hb.x*wn.x + hb.y*wn.y + hb.z*wn.z + hb.w*wn.w;
            aR[2] += hc.x*wr.x + hc.y*wr.y + hc.z*wr.z + hc.w*wr.w;
            aZ[2] += hc.x*wz.x + hc.y*wz.y + hc.z*wz.z + hc.w*wz.w;
            aN[2] += hc.x*wn.x + hc.y*wn.y + hc.z*wn.z + hc.w*wn.w;
            aR[3] += hd.x*wr.x + hd.y*wr.y + hd.z*wr.z + hd.w*wr.w;
            aZ[3] += hd.x*wz.x + hd.y*wz.y + hd.z*wz.z + hd.w*wz.w;
            aN[3] += hd.x*wn.x + hd.y*wn.y + hd.z*wn.z + hd.w*wn.w;
        }
        // reduce over kh (lane bits 2..5)
#pragma unroll
        for (int r = 0; r < 4; ++r) {
            aR[r] += __shfl_xor(aR[r], 4);  aR[r] += __shfl_xor(aR[r], 8);
            aR[r] += __shfl_xor(aR[r], 16); aR[r] += __shfl_xor(aR[r], 32);
            aZ[r] += __shfl_xor(aZ[r], 4);  aZ[r] += __shfl_xor(aZ[r], 8);
            aZ[r] += __shfl_xor(aZ[r], 16); aZ[r] += __shfl_xor(aZ[r], 32);
            aN[r] += __shfl_xor(aN[r], 4);  aN[r] += __shfl_xor(aN[r], 8);
            aN[r] += __shfl_xor(aN[r], 16); aN[r] += __shfl_xor(aN[r], 32);
        }
        if (kh == 0) {
#pragma unroll
            for (int r = 0; r < 4; ++r) {
                int n = ng * 4 + r;
                float rr  = sigmf(gpre[r * 3 + 0] + bR + aR[r]);
                float zz  = sigmf(gpre[r * 3 + 1] + bZ + aZ[r]);
                float nn2 = tanhf(gpre[r * 3 + 2] + bN + rr * aN[r]);
                float hp  = hlds[n * 576 + (j >> 5) * 36 + (j & 31)];
                float hnew = (1.f - zz) * nn2 + zz * hp;
                __hip_atomic_store(&hout[n * 512 + j], hnew, __ATOMIC_RELAXED,
                                   __HIP_MEMORY_SCOPE_AGENT);
                enc[(size_t)(n * SRC + s) * 1024 + z * 512 + j] = hnew;
            }
        }
        __syncthreads();   // drains vmcnt(0) per wave -> all stores at coherence point
        // ---- flag-array barrier: store own flag, wave 0 polls all 128 ----
        if (tid == 0)
            __hip_atomic_store(&fl[t * 128 + b1], 1u, __ATOMIC_RELAXED,
                               __HIP_MEMORY_SCOPE_AGENT);
        if (tid < 64) {
            const unsigned int* ft = fl + t * 128;
            for (;;) {
                unsigned int a = __hip_atomic_load(&ft[tid], __ATOMIC_RELAXED,
                                                   __HIP_MEMORY_SCOPE_AGENT);
                unsigned int b = __hip_atomic_load(&ft[64 + tid], __ATOMIC_RELAXED,
                                                   __HIP_MEMORY_SCOPE_AGENT);
                if (__all(a != 0u && b != 0u)) break;
                __builtin_amdgcn_s_sleep(1);
            }
        }
        __syncthreads();
    }
}

// ---------------- persistent decoder recurrence (flag barrier, 30 steps) ------
__global__ __launch_bounds__(512) void dec_scan_kernel(
    const float* __restrict__ gi, const float* __restrict__ Whh,
    const float* __restrict__ bhh, const float* __restrict__ h0,
    float* __restrict__ hall, unsigned int* __restrict__ flags) {
    const int b1 = blockIdx.x;
    const int j0 = b1 * 4;
    __shared__ float hlds[32 * 576];
    const int tid = threadIdx.x;
    const int jl = tid & 3;
    const int kh = (tid >> 2) & 15;
    const int ng = tid >> 6;
    const int j  = j0 + jl;
    const int kbase = kh * 36;

    float4 wreg[3][8];
#pragma unroll
    for (int g = 0; g < 3; ++g) {
        const float* wp = Whh + (size_t)(g * 512 + j) * 512 + kh * 32;
#pragma unroll
        for (int i = 0; i < 8; ++i) wreg[g][i] = *(const float4*)&wp[i * 4];
    }
    const float bR = bhh[j], bZ = bhh[512 + j], bN = bhh[1024 + j];

    for (int t = 0; t < TDD; ++t) {
        const float* hin = t ? (hall + (size_t)(t - 1) * NB * 512) : h0;
        float* hout = hall + (size_t)t * NB * 512;

        float gpre[12];
        if (kh == 0) {
#pragma unroll
            for (int r = 0; r < 4; ++r) {
                const float* gir = gi + (size_t)(t * NB + ng * 4 + r) * G3 + j;
                gpre[r * 3 + 0] = gir[0];
                gpre[r * 3 + 1] = gir[512];
                gpre[r * 3 + 2] = gir[1024];
            }
        }

        const unsigned long long* hin8 = (const unsigned long long*)hin;
        for (int idx = tid; idx < 32 * 256; idx += 512) {
            unsigned long long uv = __hip_atomic_load(&hin8[idx], __ATOMIC_RELAXED,
                                                      __HIP_MEMORY_SCOPE_AGENT);
            union { unsigned long long u; float f[2]; } cv; cv.u = uv;
            int nn = idx >> 8, kk = (idx & 255) << 1;
            int off = nn * 576 + (kk >> 5) * 36 + (kk & 31);
            hlds[off] = cv.f[0];
            hlds[off + 1] = cv.f[1];
        }
        __syncthreads();

        float aR[4] = {0.f, 0.f, 0.f, 0.f};
        float aZ[4] = {0.f, 0.f, 0.f, 0.f};
        float aN[4] = {0.f, 0.f, 0.f, 0.f};
        const float* h0p = &hlds[(ng * 4 + 0) * 576 + kbase];
        const float* h1p = &hlds[(ng * 4 + 1) * 576 + kbase];
        const float* h2p = &hlds[(ng * 4 + 2) * 576 + kbase];
        const float* h3p = &hlds[(ng * 4 + 3) * 576 + kbase];
#pragma unroll
        for (int i = 0; i < 8; ++i) {
            float4 wr = wreg[0][i], wz = wreg[1][i], wn = wreg[2][i];
            float4 ha = *(const float4*)&h0p[i * 4];
            float4 hb = *(const float4*)&h1p[i * 4];
            float4 hc = *(const float4*)&h2p[i * 4];
            float4 hd = *(const float4*)&h3p[i * 4];
            aR[0] += ha.x*wr.x + ha.y*wr.y + ha.z*wr.z + ha.w*wr.w;
            aZ[0] += ha.x*wz.x + ha.y*wz.y + ha.z*wz.z + ha.w*wz.w;
            aN[0] += ha.x*wn.x + ha.y*wn.y + ha.z*wn.z + ha.w*wn.w;
            aR[1] += hb.x*wr.x + hb.y*wr.y + hb.z*wr.z + hb.w*wr.w;
            aZ[1] += hb.x*wz.x + hb.y*wz.y + hb.z*wz.z + hb.w*wz.w;
            aN[1] += hb.x*wn.x + hb.y*wn.y + hb.z*wn.z + hb.w*wn.w;
            aR[2] += hc.x*wr.x + hc.y*wr.y + hc.z*wr.z + hc.w*wr.w;
            aZ[2] += hc.x*wz.x + hc.y*wz.y + hc.z*wz.z + hc.w*wz.w;
            aN[2] += hc.x*wn.x + hc.y*wn.y + hc.z*wn.z + hc.w*wn.w;
            aR[3] += hd.x*wr.x + hd.y*wr.y + hd.z*wr.z + hd.w*wr.w;
            aZ[3] += hd.x*wz.x + hd.y*wz.y + hd.z*wz.z + hd.w*wz.w;
            aN[3] += hd.x*wn.x + hd.y*wn.y + hd.z*wn.z + hd.w*wn.w;
        }
#pragma unroll
        for (int r = 0; r < 4; ++r) {
            aR[r] += __shfl_xor(aR[r], 4);  aR[r] += __shfl_xor(aR[r], 8);
            aR[r] += __shfl_xor(aR[r], 16); aR[r] += __shfl_xor(aR[r], 32);
            aZ[r] += __shfl_xor(aZ[r], 4);  aZ[r] += __shfl_xor(aZ[r], 8);
            aZ[r] += __shfl_xor(aZ[r], 16); aZ[r] += __shfl_xor(aZ[r], 32);
            aN[r] += __shfl_xor(aN[r], 4);  aN[r] += __shfl_xor(aN[r], 8);
            aN[r] += __shfl_xor(aN[r], 16); aN[r] += __shfl_xor(aN[r], 32);
        }
        if (kh == 0) {
#pragma unroll
            for (int r = 0; r < 4; ++r) {
                int n = ng * 4 + r;
                float rr  = sigmf(gpre[r * 3 + 0] + bR + aR[r]);
                float zz  = sigmf(gpre[r * 3 + 1] + bZ + aZ[r]);
                float nn2 = tanhf(gpre[r * 3 + 2] + bN + rr * aN[r]);
                float hp  = hlds[n * 576 + (j >> 5) * 36 + (j & 31)];
                float hnew = (1.f - zz) * nn2 + zz * hp;
                __hip_atomic_store(&hout[n * 512 + j], hnew, __ATOMIC_RELAXED,
                                   __HIP_MEMORY_SCOPE_AGENT);
            }
        }
        __syncthreads();
        if (tid == 0)
            __hip_atomic_store(&flags[t * 128 + b1], 1u, __ATOMIC_RELAXED,
                               __HIP_MEMORY_SCOPE_AGENT);
        if (tid < 64) {
            const unsigned int* ft = flags + t * 128;
            for (;;) {
                unsigned int a = __hip_atomic_load(&ft[tid], __ATOMIC_RELAXED,
                                                   __HIP_MEMORY_SCOPE_AGENT);
                unsigned int b = __hip_atomic_load(&ft[64 + tid], __ATOMIC_RELAXED,
                                                   __HIP_MEMORY_SCOPE_AGENT);
                if (__all(a != 0u && b != 0u)) break;
                __builtin_amdgcn_s_sleep(1);
            }
        }
        __syncthreads();
    }
}

// key_proj: kp[(n*SRC+s)*512 + c] = sum_k enc[row][k]*Wk[k*512+c]. 8 rows/block.
__global__ __launch_bounds__(256) void keyproj_kernel(const float* __restrict__ enc,
                                                      const float* __restrict__ Wk,
                                                      float* __restrict__ kp) {
    __shared__ float sx[8][1024];
    int tid = threadIdx.x;
    int g0 = blockIdx.x * 8;
    for (int i = tid; i < 8 * 1024; i += 256)
        sx[i >> 10][i & 1023] = enc[(size_t)(g0 + (i >> 10)) * 1024 + (i & 1023)];
    __syncthreads();
    int c = blockIdx.y * 256 + tid;
    float acc[8];
#pragma unroll
    for (int r = 0; r < 8; ++r) acc[r] = 0.f;
    for (int k = 0; k < 1024; k += 4) {
        float w0 = Wk[(size_t)(k + 0) * 512 + c];
        float w1 = Wk[(size_t)(k + 1) * 512 + c];
        float w2 = Wk[(size_t)(k + 2) * 512 + c];
        float w3 = Wk[(size_t)(k + 3) * 512 + c];
#pragma unroll
        for (int r = 0; r < 8; ++r) {
            float4 x4 = *(const float4*)&sx[r][k];
            acc[r] += x4.x * w0 + x4.y * w1 + x4.z * w2 + x4.w * w3;
        }
    }
#pragma unroll
    for (int r = 0; r < 8; ++r) kp[(size_t)(g0 + r) * 512 + c] = acc[r];
}

// q_all[tn][c] = battn[c] + hD_all[tn] . Wd[:,c]; 8 rows/block, grid (120,2)
__global__ __launch_bounds__(256) void qall_kernel(const float* __restrict__ hall,
                                                   const float* __restrict__ Wd,
                                                   const float* __restrict__ battn,
                                                   float* __restrict__ qall) {
    __shared__ float sx[8][512];
    int tid = threadIdx.x;
    int g0 = blockIdx.x * 8;
    for (int i = tid; i < 8 * 512; i += 256)
        sx[i >> 9][i & 511] = hall[(size_t)(g0 + (i >> 9)) * 512 + (i & 511)];
    __syncthreads();
    int c = blockIdx.y * 256 + tid;
    float b = battn[c];
    float acc[8];
#pragma unroll
    for (int r = 0; r < 8; ++r) acc[r] = b;
    for (int k = 0; k < 512; k += 4) {
        float w0 = Wd[(size_t)(k + 0) * 512 + c];
        float w1 = Wd[(size_t)(k + 1) * 512 + c];
        float w2 = Wd[(size_t)(k + 2) * 512 + c];
        float w3 = Wd[(size_t)(k + 3) * 512 + c];
#pragma unroll
        for (int r = 0; r < 8; ++r) {
            float4 x4 = *(const float4*)&sx[r][k];
            acc[r] += x4.x * w0 + x4.y * w1 + x4.z * w2 + x4.w * w3;
        }
    }
#pragma unroll
    for (int r = 0; r < 8; ++r) qall[(size_t)(g0 + r) * 512 + c] = acc[r];
}

// e_all[(tn)*SRC+s] = v . tanh(kp[n,s,:] + q_all[tn]) + mask ; 4 rows/block
__global__ __launch_bounds__(256) void escoreall_kernel(const float* __restrict__ kp,
                                                        const float* __restrict__ qall,
                                                        const float* __restrict__ vvec,
                                                        const float* __restrict__ mask,
                                                        float* __restrict__ e) {
    __shared__ float sq[512];
    int tid = threadIdx.x;
    int row0 = blockIdx.x * 4;
    int tn = row0 / SRC;    // 4 | SRC so all 4 rows share tn
    int n = tn % NB;
    sq[tid] = qall[(size_t)tn * 512 + tid];
    sq[256 + tid] = qall[(size_t)tn * 512 + 256 + tid];
    __syncthreads();
    int w = tid >> 6, lane = tid & 63;
    int row = row0 + w;
    int s = row % SRC;
    const float* kpr = kp + (size_t)(n * SRC + s) * 512;
    float acc = 0.f;
#pragma unroll
    for (int i = 0; i < 8; ++i) {
        int d = lane + i * 64;
        acc += vvec[d] * tanhf(kpr[d] + sq[d]);
    }
    for (int off = 32; off; off >>= 1) acc += __shfl_down(acc, off, 64);
    if (lane == 0) e[row] = acc + (1.f - mask[n * SRC + s]) * (-1e10f);
}

// softmax over SRC per row, in place. block per row.
__global__ __launch_bounds__(256) void softmaxS_kernel(float* __restrict__ e) {
    __shared__ float red[256];
    int n = blockIdx.x, tid = threadIdx.x;
    float* row = e + (size_t)n * SRC;
    float m = -3.4e38f;
    for (int s = tid; s < SRC; s += 256) m = fmaxf(m, row[s]);
    red[tid] = m; __syncthreads();
    for (int off = 128; off; off >>= 1) { if (tid < off) red[tid] = fmaxf(red[tid], red[tid + off]); __syncthreads(); }
    m = red[0]; __syncthreads();
    float sum = 0.f;
    for (int s = tid; s < SRC; s += 256) sum += expf(row[s] - m);
    red[tid] = sum; __syncthreads();
    for (int off = 128; off; off >>= 1) { if (tid < off) red[tid] += red[tid + off]; __syncthreads(); }
    float inv = 1.f / red[0]; __syncthreads();
    for (int s = tid; s < SRC; s += 256) row[s] = expf(row[s] - m) * inv;
}

// ctx_all[(t*NB+n)*1024+d] = sum_s attn[(t*NB+n)*SRC+s]*enc[n,s,d]; grid (32,4)
__global__ __launch_bounds__(256) void ctxall_kernel(const float* __restrict__ attn,
                                                     const float* __restrict__ enc,
                                                     float* __restrict__ ctxall) {
    __shared__ float sa[TDD * SRC];   // 48 KB
    int n = blockIdx.x, tid = threadIdx.x;
    for (int i = tid; i < TDD * SRC; i += 256) {
        int t = i / SRC, s = i - t * SRC;
        sa[i] = attn[(size_t)(t * NB + n) * SRC + s];
    }
    __syncthreads();
    int d = blockIdx.y * 256 + tid;
    const float* er = enc + (size_t)n * SRC * 1024 + d;
    float acc[TDD];
#pragma unroll
    for (int t = 0; t < TDD; ++t) acc[t] = 0.f;
    for (int s = 0; s < SRC; s += 4) {
        float e0 = er[(size_t)(s + 0) * 1024];
        float e1 = er[(size_t)(s + 1) * 1024];
        float e2 = er[(size_t)(s + 2) * 1024];
        float e3 = er[(size_t)(s + 3) * 1024];
#pragma unroll
        for (int t = 0; t < TDD; ++t) {
            float4 a4 = *(const float4*)&sa[t * SRC + s];
            acc[t] += a4.x * e0 + a4.y * e1 + a4.z * e2 + a4.w * e3;
        }
    }
#pragma unroll
    for (int t = 0; t < TDD; ++t) ctxall[(size_t)(t * NB + n) * 1024 + d] = acc[t];
}

// pgen_all[tn] = sigmoid([xi, ctx, h] . Wp + bp); block per tn, grid 960
__global__ __launch_bounds__(256) void pgenall_kernel(const int* __restrict__ trg_ids,
                                                      const float* __restrict__ embed,
                                                      const float* __restrict__ ctxall,
                                                      const float* __restrict__ hall,
                                                      const float* __restrict__ Wp,
                                                      const float* __restrict__ bp,
                                                      float* __restrict__ pgenall) {
    __shared__ float red[256];
    int tn = blockIdx.x, tid = threadIdx.x;
    int t = tn / NB, n = tn % NB;
    int tok = trg_ids[n * TDD + t];
    float acc = 0.f;
    for (int i = tid; i < 1792; i += 256) {
        float val;
        if (i < 256) val = embed[(size_t)tok * EMB + i];
        else if (i < 1280) val = ctxall[(size_t)tn * 1024 + (i - 256)];
        else val = hall[(size_t)tn * 512 + (i - 1280)];
        acc += val * Wp[i];
    }
    red[tid] = acc; __syncthreads();
    for (int off = 128; off; off >>= 1) { if (tid < off) red[tid] += red[tid + off]; __syncthreads(); }
    if (tid == 0) pgenall[tn] = 1.f / (1.f + expf(-(red[0] + bp[0])));
}

// hid1_all[tn][c] = b1[c] + [h,ctx] . W1[:,c]; 8 rows/block, grid (120,2)
__global__ __launch_bounds__(256) void hid1all_kernel(const float* __restrict__ hall,
                                                      const float* __restrict__ ctxall,
                                                      const float* __restrict__ W1,
                                                      const float* __restrict__ b1,
                                                      float* __restrict__ hid1all) {
    __shared__ float sc[8][1536];   // 48 KB
    int tid = threadIdx.x;
    int g0 = blockIdx.x * 8;
    for (int i = tid; i < 8 * 512; i += 256)
        sc[i >> 9][i & 511] = hall[(size_t)(g0 + (i >> 9)) * 512 + (i & 511)];
    for (int i = tid; i < 8 * 1024; i += 256)
        sc[i >> 10][512 + (i & 1023)] = ctxall[(size_t)(g0 + (i >> 10)) * 1024 + (i & 1023)];
    __syncthreads();
    int c = blockIdx.y * 256 + tid;
    float acc[8];
    float b = b1[c];
#pragma unroll
    for (int r = 0; r < 8; ++r) acc[r] = b;
    for (int k = 0; k < 1536; k += 4) {
        float w0 = W1[(size_t)(k + 0) * 512 + c];
        float w1 = W1[(size_t)(k + 1) * 512 + c];
        float w2 = W1[(size_t)(k + 2) * 512 + c];
        float w3 = W1[(size_t)(k + 3) * 512 + c];
#pragma unroll
        for (int r = 0; r < 8; ++r) {
            float4 x4 = *(const float4*)&sc[r][k];
            acc[r] += x4.x * w0 + x4.y * w1 + x4.z * w2 + x4.w * w3;
        }
    }
#pragma unroll
    for (int r = 0; r < 8; ++r) hid1all[(size_t)(g0 + r) * 512 + c] = acc[r];
}

// logits_all: 32-row groups; grid (196, 30). thread per j, 32 rows in registers.
__global__ __launch_bounds__(256) void logitsall_kernel(const float* __restrict__ hid1,
                                                        const float* __restrict__ W2,
                                                        const float* __restrict__ b2,
                                                        float* __restrict__ logits) {
    __shared__ float sh[32][512];   // 64 KB
    int tid = threadIdx.x;
    int r0 = blockIdx.y * 32;
    for (int i = tid; i < 32 * 512; i += 256) sh[i >> 9][i & 511] = hid1[(size_t)r0 * 512 + i];
    __syncthreads();
    int j = blockIdx.x * 256 + tid;
    if (j >= VSZ) return;
    float acc[32];
#pragma unroll
    for (int r = 0; r < 32; ++r) acc[r] = 0.f;
    for (int k = 0; k < 512; k += 4) {
        float w0 = W2[(size_t)(k + 0) * VSZ + j];
        float w1 = W2[(size_t)(k + 1) * VSZ + j];
        float w2 = W2[(size_t)(k + 2) * VSZ + j];
        float w3 = W2[(size_t)(k + 3) * VSZ + j];
#pragma unroll
        for (int r = 0; r < 32; ++r) {
            float4 h4 = *(const float4*)&sh[r][k];
            acc[r] += h4.x * w0 + h4.y * w1 + h4.z * w2 + h4.w * w3;
        }
    }
    float bb = b2[j];
#pragma unroll
    for (int r = 0; r < 32; ++r) logits[(size_t)(r0 + r) * VSZ + j] = acc[r] + bb;
}

// softmax over V, scale by p_gen, write out row; block per tn
__global__ __launch_bounds__(1024) void outall_kernel(const float* __restrict__ logits,
                                                      const float* __restrict__ pgenall,
                                                      float* __restrict__ out) {
    __shared__ float red[1024];
    int tn = blockIdx.x, tid = threadIdx.x;
    int t = tn / NB, n = tn % NB;
    const float* lrow = logits + (size_t)tn * VSZ;
    float m = -3.4e38f;
    for (int j = tid; j < VSZ; j += 1024) m = fmaxf(m, lrow[j]);
    red[tid] = m; __syncthreads();
    for (int off = 512; off; off >>= 1) { if (tid < off) red[tid] = fmaxf(red[tid], red[tid + off]); __syncthreads(); }
    m = red[0]; __syncthreads();
    float sum = 0.f;
    for (int j = tid; j < VSZ; j += 1024) sum += expf(lrow[j] - m);
    red[tid] = sum; __syncthreads();
    for (int off = 512; off; off >>= 1) { if (tid < off) red[tid] += red[tid + off]; __syncthreads(); }
    float inv = pgenall[tn] / red[0];
    float* orow = out + (size_t)(n * TDD + t) * VE;
    for (int j = tid; j < VE; j += 1024) orow[j] = (j < VSZ) ? expf(lrow[j] - m) * inv : 0.f;
}

// out[n, t, ptr[n,s]] += (1-p_gen[tn]) * attn[tn,s] for all t,n,s
__global__ __launch_bounds__(256) void scatterall_kernel(const int* __restrict__ ptr,
                                                         const float* __restrict__ attn,
                                                         const float* __restrict__ pgenall,
                                                         float* __restrict__ out) {
    int f = blockIdx.x * 256 + threadIdx.x;
    if (f >= TDD * NB * SRC) return;
    int tn = f / SRC;
    int s = f - tn * SRC;
    int t = tn / NB, n = tn % NB;
    float w = (1.f - pgenall[tn]) * attn[f];
    atomicAdd(&out[(size_t)(n * TDD + t) * VE + ptr[n * SRC + s]], w);
}

extern "C" void kernel_launch(void* const* d_in, const int* in_sizes, int n_in,
                              void* d_out, int out_size, void* d_ws, size_t ws_size,
                              hipStream_t stream) {
    const int*   src_ids  = (const int*)d_in[0];
    const float* src_mask = (const float*)d_in[1];
    const int*   trg_ids  = (const int*)d_in[2];
    const int*   ptr_idx  = (const int*)d_in[3];
    const float* embed    = (const float*)d_in[4];
    const float* Wih_f = (const float*)d_in[5];
    const float* Whh_f = (const float*)d_in[6];
    const float* bih_f = (const float*)d_in[7];
    const float* bhh_f = (const float*)d_in[8];
    const float* Wih_b = (const float*)d_in[9];
    const float* Whh_b = (const float*)d_in[10];
    const float* bih_b = (const float*)d_in[11];
    const float* bhh_b = (const float*)d_in[12];
    const float* Wih_d = (const float*)d_in[13];
    const float* Whh_d = (const float*)d_in[14];
    const float* bih_d = (const float*)d_in[15];
    const float* bhh_d = (const float*)d_in[16];
    const float* Wk    = (const float*)d_in[17];
    const float* Wd    = (const float*)d_in[18];
    const float* battn = (const float*)d_in[19];
    const float* vvec  = (const float*)d_in[20];
    const float* W1    = (const float*)d_in[21];
    const float* b1    = (const float*)d_in[22];
    const float* W2    = (const float*)d_in[23];
    const float* b2    = (const float*)d_in[24];
    const float* Wp    = (const float*)d_in[25];
    const float* bp    = (const float*)d_in[26];
    float* out = (float*)d_out;

    float* w = (float*)d_ws;
    float* WihTf = w; w += 256 * G3;
    float* WihTb = w; w += 256 * G3;
    float* WihTd = w; w += 256 * G3;
    float* giF = w; w += (size_t)SRC * NB * G3;   // dead after enc_scan
    float* giB = w; w += (size_t)SRC * NB * G3;   // dead after enc_scan
    float* giD = w; w += (size_t)TDD * NB * G3;   // dead after dec_scan
    float* enc = w; w += (size_t)NB * SRC * 1024; // dead after ctx_all
    float* kp  = w; w += (size_t)NB * SRC * 512;  // dead after escore_all
    float* hF0 = w; w += NB * HE;
    float* hF1 = w; w += NB * HE;
    float* hB0 = w; w += NB * HE;
    float* hB1 = w; w += NB * HE;
    float* h0d = w; w += NB * HD;
    float* hD_all = w; w += (size_t)TDD * NB * HD;
    float* q_all  = w; w += (size_t)TDD * NB * 512;
    float* e_all  = w; w += (size_t)TDD * NB * SRC;
    float* ctx_all = w; w += (size_t)TDD * NB * 1024;
    float* hid1_all = w; w += (size_t)TDD * NB * 512;
    float* pgen_all = w; w += 1024;
    unsigned int* encflag = (unsigned int*)w; w += 2 * SRC * 128;
    unsigned int* decflag = (unsigned int*)w; w += TDD * 128;
    // logits_all (960*50000 = 48M floats) aliases giF..enc-prefix (dead by then)
    float* logits_all = giF;

    // ---- weight transposes (WihT x3 for gi) ----
    transpose_kernel<<<(G3 * 256 + 255) / 256, 256, 0, stream>>>(Wih_f, WihTf, G3, 256);
    transpose_kernel<<<(G3 * 256 + 255) / 256, 256, 0, stream>>>(Wih_b, WihTb, G3, 256);
    transpose_kernel<<<(G3 * 256 + 255) / 256, 256, 0, stream>>>(Wih_d, WihTd, G3, 256);

    // ---- input-gate precompute ----
    gi_kernel<<<dim3(SRC * NB / 16, 6), 256, 0, stream>>>(src_ids, embed, WihTf, bih_f, giF, SRC);
    gi_kernel<<<dim3(SRC * NB / 16, 6), 256, 0, stream>>>(src_ids, embed, WihTb, bih_b, giB, SRC);
    gi_kernel<<<dim3(TDD * NB / 16, 6), 256, 0, stream>>>(trg_ids, embed, WihTd, bih_d, giD, TDD);

    hipMemsetAsync(hF0, 0, NB * HE * sizeof(float), stream);
    hipMemsetAsync(hB0, 0, NB * HE * sizeof(float), stream);
    hipMemsetAsync(h0d, 0, NB * HD * sizeof(float), stream);
    hipMemsetAsync(encflag, 0, (2 * SRC * 128 + TDD * 128) * sizeof(unsigned int), stream);

    // ---- encoder scan: persistent, flag-array barrier ----
    enc_scan_kernel<<<2 * ENC_PER_DIR, 512, 0, stream>>>(
        giF, giB, Whh_f, Whh_b, bhh_f, bhh_b,
        hF0, hF1, hB0, hB1, enc, encflag);

    keyproj_kernel<<<dim3(NB * SRC / 8, 2), 256, 0, stream>>>(enc, Wk, kp);

    // ---- decoder recurrence: persistent (30 steps, 128 blocks) ----
    dec_scan_kernel<<<DEC_NBLK, 512, 0, stream>>>(giD, Whh_d, bhh_d, h0d, hD_all, decflag);

    // ---- fully batched decoder head over all 30 steps ----
    qall_kernel<<<dim3(TDD * NB / 8, 2), 256, 0, stream>>>(hD_all, Wd, battn, q_all);
    escoreall_kernel<<<TDD * NB * SRC / 4, 256, 0, stream>>>(kp, q_all, vvec, src_mask, e_all);
    softmaxS_kernel<<<TDD * NB, 256, 0, stream>>>(e_all);
    ctxall_kernel<<<dim3(NB, 4), 256, 0, stream>>>(e_all, enc, ctx_all);
    pgenall_kernel<<<TDD * NB, 256, 0, stream>>>(trg_ids, embed, ctx_all, hD_all, Wp, bp, pgen_all);
    hid1all_kernel<<<dim3(TDD * NB / 8, 2), 256, 0, stream>>>(hD_all, ctx_all, W1, b1, hid1_all);
    logitsall_kernel<<<dim3((VSZ + 255) / 256, TDD), 256, 0, stream>>>(hid1_all, W2, b2, logits_all);
    outall_kernel<<<TDD * NB, 1024, 0, stream>>>(logits_all, pgen_all, out);
    scatterall_kernel<<<(TDD * NB * SRC + 255) / 256, 256, 0, stream>>>(ptr_idx, e_all, pgen_all, out);
}